// Round 1
// baseline (186.875 us; speedup 1.0000x reference)
//
#include <hip/hip_runtime.h>
#include <hip/hip_bf16.h>

// 16-qubit statevector sim, batch 64.
// idx bit p ("pos p") = bit p of flattened state index; wire w <-> pos 15-w (wire 0 = MSB).
// Workspace layout: [0,32MB) state float2; then Us (64*2*16*8 f32), crx (2*16*2 f32), feats (64*16 f32).

#define NQ 16
#define DIM 65536
#define BATCH 64

// ---------------- gate helpers (thread-local register amps, fully unrolled) ----------------

// general 1q gate on register bit RB (16 amps per thread)
template<int RB>
__device__ __forceinline__ void g1q_reg(float* sr, float* si, const float* U) {
  float u00r=U[0],u00i=U[1],u01r=U[2],u01i=U[3],u10r=U[4],u10i=U[5],u11r=U[6],u11i=U[7];
#pragma unroll
  for (int k = 0; k < 8; ++k) {
    int lo = k & ((1<<RB)-1);
    int j0 = ((k >> RB) << (RB+1)) | lo;
    int j1 = j0 | (1<<RB);
    float a0r=sr[j0], a0i=si[j0], a1r=sr[j1], a1i=si[j1];
    sr[j0] = u00r*a0r - u00i*a0i + u01r*a1r - u01i*a1i;
    si[j0] = u00r*a0i + u00i*a0r + u01r*a1i + u01i*a1r;
    sr[j1] = u10r*a0r - u10i*a0i + u11r*a1r - u11i*a1i;
    si[j1] = u10r*a0i + u10i*a0r + u11r*a1i + u11i*a1r;
  }
}

// general 1q gate on lane bit LB (partner via shuffle)
template<int LB>
__device__ __forceinline__ void g1q_lane(float* sr, float* si, const float* U, int lane) {
  int side = (lane >> LB) & 1;
  float umr = side ? U[6] : U[0], umi = side ? U[7] : U[1];
  float upr = side ? U[4] : U[2], upi = side ? U[5] : U[3];
#pragma unroll
  for (int j = 0; j < 16; ++j) {
    float pr = __shfl_xor(sr[j], 1<<LB, 64);
    float pi = __shfl_xor(si[j], 1<<LB, 64);
    float mr = sr[j], mi = si[j];
    sr[j] = umr*mr - umi*mi + upr*pr - upi*pi;
    si[j] = umr*mi + umi*mr + upr*pi + upi*pr;
  }
}

// CRX: ctrl reg bit CB, target reg bit TB.  RX = [[c,-is],[-is,c]]
template<int CB, int TB>
__device__ __forceinline__ void crx_reg_reg(float* sr, float* si, float c, float s) {
  constexpr int lo = (CB < TB ? CB : TB), hi = (CB < TB ? TB : CB);
#pragma unroll
  for (int k = 0; k < 4; ++k) {
    int t2 = ((k >> lo) << (lo+1)) | (k & ((1<<lo)-1));
    int t3 = ((t2 >> hi) << (hi+1)) | (t2 & ((1<<hi)-1));
    int j0 = t3 | (1<<CB);
    int j1 = j0 | (1<<TB);
    float a0r=sr[j0],a0i=si[j0],a1r=sr[j1],a1i=si[j1];
    sr[j0] = c*a0r + s*a1i; si[j0] = c*a0i - s*a1r;
    sr[j1] = c*a1r + s*a0i; si[j1] = c*a1i - s*a0r;
  }
}

// CRX: ctrl = per-thread predicate, target reg bit TB
template<int TB>
__device__ __forceinline__ void crx_pred_reg(float* sr, float* si, float c, float s, bool pred) {
#pragma unroll
  for (int k = 0; k < 8; ++k) {
    int lo2 = k & ((1<<TB)-1);
    int j0 = ((k >> TB) << (TB+1)) | lo2;
    int j1 = j0 | (1<<TB);
    float a0r=sr[j0],a0i=si[j0],a1r=sr[j1],a1i=si[j1];
    float n0r = c*a0r + s*a1i, n0i = c*a0i - s*a1r;
    float n1r = c*a1r + s*a0i, n1i = c*a1i - s*a0r;
    sr[j0] = pred ? n0r : a0r; si[j0] = pred ? n0i : a0i;
    sr[j1] = pred ? n1r : a1r; si[j1] = pred ? n1i : a1i;
  }
}

// CRX: ctrl reg bit CB, target lane bit LB (symmetric RX: new = c*mine + s*(p.i, -p.r))
template<int CB, int LB>
__device__ __forceinline__ void crx_reg_lane(float* sr, float* si, float c, float s) {
#pragma unroll
  for (int k = 0; k < 8; ++k) {
    int lo2 = k & ((1<<CB)-1);
    int j = ((((k >> CB) << (CB+1)) | lo2)) | (1<<CB);
    float pr = __shfl_xor(sr[j], 1<<LB, 64);
    float pi = __shfl_xor(si[j], 1<<LB, 64);
    float mr = sr[j], mi = si[j];
    sr[j] = c*mr + s*pi;
    si[j] = c*mi - s*pr;
  }
}

// CRX: ctrl = per-thread predicate, target lane bit LB
template<int LB>
__device__ __forceinline__ void crx_pred_lane(float* sr, float* si, float c, float s, bool pred) {
#pragma unroll
  for (int j = 0; j < 16; ++j) {
    float pr = __shfl_xor(sr[j], 1<<LB, 64);
    float pi = __shfl_xor(si[j], 1<<LB, 64);
    float mr = sr[j], mi = si[j];
    sr[j] = pred ? (c*mr + s*pi) : mr;
    si[j] = pred ? (c*mi - s*pr) : mi;
  }
}

// ---------------- prep: fused U = Rot(w[q]) * RX(x[b,q]) per (batch, layer, wire); CRX trig ----------------

__global__ void kprep(const float* __restrict__ x, const float* __restrict__ w0,
                      const float* __restrict__ x0, const float* __restrict__ w1,
                      const float* __restrict__ x1, float* __restrict__ Us,
                      float* __restrict__ crx) {
  int b = blockIdx.x;
  int t = threadIdx.x;
  if (t < 32) {
    int l = t >> 4, q = t & 15;
    const float* W = (l ? w1 : w0) + q*3;
    float xa = 0.5f * x[b*16 + q];
    float cr = cosf(xa), sx = sinf(xa);
    float phi = W[0], th = W[1], om = W[2];
    float ct = cosf(0.5f*th), stt = sinf(0.5f*th);
    float po = 0.5f*(phi+om), pm = 0.5f*(phi-om);
    float ar =  cosf(po)*ct,  ai = -sinf(po)*ct;   // a = e^{-i po} ct
    float br = -cosf(pm)*stt, bi = -sinf(pm)*stt;  // b = -e^{+i pm} st
    float cr2 = cosf(pm)*stt, ci2 = -sinf(pm)*stt; // c = e^{-i pm} st
    float dr =  cosf(po)*ct,  di =  sinf(po)*ct;   // d = e^{+i po} ct
    float* U = Us + ((size_t)(b*2 + l)*16 + q)*8;
    U[0] = ar*cr + bi*sx;   U[1] = ai*cr - br*sx;   // F00 = a*cr + b*(-i sx)
    U[2] = ai*sx + br*cr;   U[3] = -ar*sx + bi*cr;  // F01 = a*(-i sx) + b*cr
    U[4] = cr2*cr + di*sx;  U[5] = ci2*cr - dr*sx;  // F10
    U[6] = ci2*sx + dr*cr;  U[7] = -cr2*sx + di*cr; // F11
    if (b == 0) {
      float ang = 0.5f * (l ? x1[q] : x0[q]);
      crx[(l*16 + q)*2 + 0] = cosf(ang);
      crx[(l*16 + q)*2 + 1] = sinf(ang);
    }
  }
}

// ---------------- K2: strided tile {pos 0..6, 10..15}; block bits m = pos 7..9 ----------------
// applies: [layer>0: CRX w=15 of layer-1], 1q wires 0..5, CRX w=0..4
// mapping: reg r bits 0..3 -> pos 12..15; lane bits 0..3 -> pos 0..3, lane4 -> pos10, lane5 -> pos11; wv -> pos 4..6

__global__ __launch_bounds__(512) void k2(float2* __restrict__ st, const float* __restrict__ Us,
                                          const float* __restrict__ crx, int layer) {
  int blk = blockIdx.x;
  int b = blk >> 3, m = blk & 7;
  int t = threadIdx.x, lane = t & 63, wv = t >> 6;
  int idx0 = (lane & 15) | (((lane>>4)&1)<<10) | (((lane>>5)&1)<<11) | (wv<<4) | (m<<7);
  float2* S = st + (size_t)b * DIM;
  float sr[16], si[16];
  if (layer == 0) {
#pragma unroll
    for (int r = 0; r < 16; ++r) { sr[r] = 0.f; si[r] = 0.f; }
    if (idx0 == 0) sr[0] = 1.f;   // |00...0>
  } else {
#pragma unroll
    for (int r = 0; r < 16; ++r) { float2 v = S[idx0 | (r<<12)]; sr[r] = v.x; si[r] = v.y; }
    // CRX w=15 of previous layer: ctrl pos0 (lane bit0), tgt pos15 (reg bit3)
    float c = crx[((layer-1)*16 + 15)*2], s = crx[((layer-1)*16 + 15)*2 + 1];
    crx_pred_reg<3>(sr, si, c, s, (lane & 1) != 0);
  }
  const float* U = Us + (size_t)(b*2 + layer)*16*8;
  // 1q wires 0..3 -> reg bits 3..0; wires 4,5 -> lane bits 5,4
  g1q_reg<3>(sr, si, U + 0*8);
  g1q_reg<2>(sr, si, U + 1*8);
  g1q_reg<1>(sr, si, U + 2*8);
  g1q_reg<0>(sr, si, U + 3*8);
  g1q_lane<5>(sr, si, U + 4*8, lane);
  g1q_lane<4>(sr, si, U + 5*8, lane);
  const float* cx = crx + layer*32;
  crx_reg_reg<3,2>(sr, si, cx[0], cx[1]);                        // w=0: ctrl pos15, tgt pos14
  crx_reg_reg<2,1>(sr, si, cx[2], cx[3]);                        // w=1
  crx_reg_reg<1,0>(sr, si, cx[4], cx[5]);                        // w=2
  crx_reg_lane<0,5>(sr, si, cx[6], cx[7]);                       // w=3: ctrl pos12(reg0), tgt pos11(lane5)
  crx_pred_lane<4>(sr, si, cx[8], cx[9], (lane & 32) != 0);      // w=4: ctrl pos11(lane5), tgt pos10(lane4)
#pragma unroll
  for (int r = 0; r < 16; ++r) S[idx0 | (r<<12)] = make_float2(sr[r], si[r]);
}

// ---------------- K13: contiguous tile pos 0..12; block bits m = pos 13..15 ----------------
// applies: 1q wires 6..15, CRX w=5..14
// mapping: reg r -> pos 0..3; lane -> pos 4..9; wv -> pos 10..12

__global__ __launch_bounds__(512) void k13(float2* __restrict__ st, const float* __restrict__ Us,
                                           const float* __restrict__ crx, int layer) {
  int blk = blockIdx.x;
  int b = blk >> 3, m = blk & 7;
  int t = threadIdx.x, lane = t & 63, wv = t >> 6;
  int idx0 = (m<<13) | (wv<<10) | (lane<<4);
  float2* S = st + (size_t)b * DIM + idx0;
  float sr[16], si[16];
#pragma unroll
  for (int r = 0; r < 16; ++r) { float2 v = S[r]; sr[r] = v.x; si[r] = v.y; }
  const float* U = Us + (size_t)(b*2 + layer)*16*8;
  // 1q wires 6..11 -> lane bits 5..0; wires 12..15 -> reg bits 3..0
  g1q_lane<5>(sr, si, U + 6*8, lane);
  g1q_lane<4>(sr, si, U + 7*8, lane);
  g1q_lane<3>(sr, si, U + 8*8, lane);
  g1q_lane<2>(sr, si, U + 9*8, lane);
  g1q_lane<1>(sr, si, U + 10*8, lane);
  g1q_lane<0>(sr, si, U + 11*8, lane);
  g1q_reg<3>(sr, si, U + 12*8);
  g1q_reg<2>(sr, si, U + 13*8);
  g1q_reg<1>(sr, si, U + 14*8);
  g1q_reg<0>(sr, si, U + 15*8);
  const float* cx = crx + layer*32;
  crx_pred_lane<5>(sr, si, cx[10], cx[11], (wv & 1) != 0);       // w=5: ctrl pos10(wv0), tgt pos9(lane5)
  crx_pred_lane<4>(sr, si, cx[12], cx[13], (lane & 32) != 0);    // w=6
  crx_pred_lane<3>(sr, si, cx[14], cx[15], (lane & 16) != 0);    // w=7
  crx_pred_lane<2>(sr, si, cx[16], cx[17], (lane & 8) != 0);     // w=8
  crx_pred_lane<1>(sr, si, cx[18], cx[19], (lane & 4) != 0);     // w=9
  crx_pred_lane<0>(sr, si, cx[20], cx[21], (lane & 2) != 0);     // w=10
  crx_pred_reg<3>(sr, si, cx[22], cx[23], (lane & 1) != 0);      // w=11: ctrl pos4(lane0), tgt pos3(reg3)
  crx_reg_reg<3,2>(sr, si, cx[24], cx[25]);                      // w=12
  crx_reg_reg<2,1>(sr, si, cx[26], cx[27]);                      // w=13
  crx_reg_reg<1,0>(sr, si, cx[28], cx[29]);                      // w=14
#pragma unroll
  for (int r = 0; r < 16; ++r) S[r] = make_float2(sr[r], si[r]);
}

// ---------------- epilogue: final CRX w=15 (layer 1) + |amp|^2 + PauliZ signed sums ----------------
// tile: free bits {0..11, 15}; block bits m = pos 12..14
// mapping: reg r bits0..2 -> pos 0..2, bit3 -> pos 15; lane -> pos 3..8; wv -> pos 9..11

__global__ __launch_bounds__(512) void kepi(const float2* __restrict__ st, const float* __restrict__ crx,
                                            float* __restrict__ feats) {
  int blk = blockIdx.x;
  int b = blk >> 3, m = blk & 7;
  int t = threadIdx.x, lane = t & 63, wv = t >> 6;
  int idx0 = (lane<<3) | (wv<<9) | (m<<12);
  const float2* S = st + (size_t)b * DIM;
  float sr[16], si[16];
#pragma unroll
  for (int r = 0; r < 16; ++r) {
    int idx = idx0 | (r & 7) | ((r>>3)<<15);
    float2 v = S[idx]; sr[r] = v.x; si[r] = v.y;
  }
  // CRX w=15, layer 1: ctrl pos0 (r bit0), tgt pos15 (r bit3)
  float c = crx[(16 + 15)*2], s = crx[(16 + 15)*2 + 1];
#pragma unroll
  for (int r = 1; r < 8; r += 2) {
    int j0 = r, j1 = r | 8;
    float a0r=sr[j0],a0i=si[j0],a1r=sr[j1],a1i=si[j1];
    sr[j0] = c*a0r + s*a1i; si[j0] = c*a0i - s*a1r;
    sr[j1] = c*a1r + s*a0i; si[j1] = c*a1i - s*a0r;
  }
  float tot=0.f, s0=0.f, s1=0.f, s2=0.f, s15=0.f;
#pragma unroll
  for (int r = 0; r < 16; ++r) {
    float p = sr[r]*sr[r] + si[r]*si[r];
    tot += p;
    s0  += (r & 1) ? -p : p;
    s1  += (r & 2) ? -p : p;
    s2  += (r & 4) ? -p : p;
    s15 += (r & 8) ? -p : p;
  }
  float f[16];
  f[15] = s0;  f[14] = s1;  f[13] = s2;  f[0] = s15;
#pragma unroll
  for (int i = 0; i < 6; ++i) f[12-i] = ((lane>>i)&1) ? -tot : tot;  // pos 3..8 -> wires 12..7
#pragma unroll
  for (int i = 0; i < 3; ++i) f[6-i]  = ((wv>>i)&1)   ? -tot : tot;  // pos 9..11 -> wires 6..4
#pragma unroll
  for (int i = 0; i < 3; ++i) f[3-i]  = ((m>>i)&1)    ? -tot : tot;  // pos 12..14 -> wires 3..1
#pragma unroll
  for (int w = 0; w < 16; ++w) {
#pragma unroll
    for (int off = 32; off; off >>= 1) f[w] += __shfl_xor(f[w], off, 64);
  }
  __shared__ float red[8][17];
  if (lane == 0) {
#pragma unroll
    for (int w = 0; w < 16; ++w) red[wv][w] = f[w];
  }
  __syncthreads();
  if (t < 16) {
    float acc = 0.f;
#pragma unroll
    for (int i = 0; i < 8; ++i) acc += red[i][t];
    atomicAdd(&feats[b*16 + t], acc);
  }
}

// ---------------- FC + log_softmax ----------------

__global__ void kfc(const float* __restrict__ feats, const float* __restrict__ fcw,
                    const float* __restrict__ fcb, float* __restrict__ out) {
  int b = blockIdx.x, t = threadIdx.x;
  __shared__ float fs[16];
  __shared__ float lg[23];
  if (t < 16) fs[t] = feats[b*16 + t];
  __syncthreads();
  if (t < 23) {
    float acc = fcb[t];
#pragma unroll
    for (int w = 0; w < 16; ++w) acc += fs[w] * fcw[t*16 + w];
    lg[t] = acc;
  }
  __syncthreads();
  if (t < 23) {
    float mx = -1e30f;
#pragma unroll
    for (int j = 0; j < 23; ++j) mx = fmaxf(mx, lg[j]);
    float Ssum = 0.f;
#pragma unroll
    for (int j = 0; j < 23; ++j) Ssum += expf(lg[j] - mx);
    out[b*23 + t] = lg[t] - mx - logf(Ssum);
  }
}

extern "C" void kernel_launch(void* const* d_in, const int* in_sizes, int n_in,
                              void* d_out, int out_size, void* d_ws, size_t ws_size,
                              hipStream_t stream) {
  const float* x   = (const float*)d_in[0];
  const float* w0  = (const float*)d_in[1];
  const float* x0  = (const float*)d_in[2];
  const float* w1  = (const float*)d_in[3];
  const float* x1  = (const float*)d_in[4];
  const float* fcw = (const float*)d_in[5];
  const float* fcb = (const float*)d_in[6];
  float* out = (float*)d_out;

  char* ws = (char*)d_ws;
  float2* st  = (float2*)ws;                                  // 64*65536*8 B = 32 MB
  float*  Us  = (float*)(ws + (size_t)BATCH * DIM * sizeof(float2)); // 64*2*16*8 f32 = 64 KB
  float*  crx = Us + (size_t)BATCH*2*16*8;                    // 2*16*2 = 64 f32
  float*  feats = crx + 64;                                   // 64*16 f32 = 4 KB

  kprep<<<BATCH, 64, 0, stream>>>(x, w0, x0, w1, x1, Us, crx);
  k2 <<<512, 512, 0, stream>>>(st, Us, crx, 0);
  k13<<<512, 512, 0, stream>>>(st, Us, crx, 0);
  k2 <<<512, 512, 0, stream>>>(st, Us, crx, 1);
  k13<<<512, 512, 0, stream>>>(st, Us, crx, 1);
  hipMemsetAsync(feats, 0, BATCH*16*sizeof(float), stream);
  kepi<<<512, 512, 0, stream>>>(st, crx, feats);
  kfc<<<BATCH, 32, 0, stream>>>(feats, fcw, fcb, out);
  (void)in_sizes; (void)n_in; (void)out_size; (void)ws_size;
}

// Round 2
// 171.228 us; speedup vs baseline: 1.0914x; 1.0914x over previous
//
#include <hip/hip_runtime.h>
#include <hip/hip_bf16.h>

// 16-qubit statevector sim, batch 64, restructured to 2 full-state passes.
// idx bit p ("pos p") = bit p of flattened state index; wire w <-> pos 15-w.
// P12: layer0 (13-bit compact stage computed redundantly per block, 2^13 amps,
//      support bits0..2=0) -> slice via LDS -> layer0 tail + layer1 head -> store state.
// P3:  load state, finish layer1, |amp|^2 + PauliZ signed sums -> feats.
// Workspace: [0,32MB) state float2; Us (64*2*16*8 f32); crx (2*16*2 f32); feats (64*16).

#define NQ 16
#define DIM 65536
#define BATCH 64

// ---------------- gate helpers (thread-local register amps, fully unrolled) ----------------

template<int RB>
__device__ __forceinline__ void g1q_reg(float* sr, float* si, const float* U) {
  float u00r=U[0],u00i=U[1],u01r=U[2],u01i=U[3],u10r=U[4],u10i=U[5],u11r=U[6],u11i=U[7];
#pragma unroll
  for (int k = 0; k < 8; ++k) {
    int lo = k & ((1<<RB)-1);
    int j0 = ((k >> RB) << (RB+1)) | lo;
    int j1 = j0 | (1<<RB);
    float a0r=sr[j0], a0i=si[j0], a1r=sr[j1], a1i=si[j1];
    sr[j0] = u00r*a0r - u00i*a0i + u01r*a1r - u01i*a1i;
    si[j0] = u00r*a0i + u00i*a0r + u01r*a1i + u01i*a1r;
    sr[j1] = u10r*a0r - u10i*a0i + u11r*a1r - u11i*a1i;
    si[j1] = u10r*a0i + u10i*a0r + u11r*a1i + u11i*a1r;
  }
}

template<int LB>
__device__ __forceinline__ void g1q_lane(float* sr, float* si, const float* U, int lane) {
  int side = (lane >> LB) & 1;
  float umr = side ? U[6] : U[0], umi = side ? U[7] : U[1];
  float upr = side ? U[4] : U[2], upi = side ? U[5] : U[3];
#pragma unroll
  for (int j = 0; j < 16; ++j) {
    float pr = __shfl_xor(sr[j], 1<<LB, 64);
    float pi = __shfl_xor(si[j], 1<<LB, 64);
    float mr = sr[j], mi = si[j];
    sr[j] = umr*mr - umi*mi + upr*pr - upi*pi;
    si[j] = umr*mi + umi*mr + upr*pi + upi*pr;
  }
}

// CRX: ctrl reg bit CB, target reg bit TB.  RX = [[c,-is],[-is,c]]
template<int CB, int TB>
__device__ __forceinline__ void crx_reg_reg(float* sr, float* si, float c, float s) {
  constexpr int lo = (CB < TB ? CB : TB), hi = (CB < TB ? TB : CB);
#pragma unroll
  for (int k = 0; k < 4; ++k) {
    int t2 = ((k >> lo) << (lo+1)) | (k & ((1<<lo)-1));
    int t3 = ((t2 >> hi) << (hi+1)) | (t2 & ((1<<hi)-1));
    int j0 = t3 | (1<<CB);
    int j1 = j0 | (1<<TB);
    float a0r=sr[j0],a0i=si[j0],a1r=sr[j1],a1i=si[j1];
    sr[j0] = c*a0r + s*a1i; si[j0] = c*a0i - s*a1r;
    sr[j1] = c*a1r + s*a0i; si[j1] = c*a1i - s*a0r;
  }
}

template<int TB>
__device__ __forceinline__ void crx_pred_reg(float* sr, float* si, float c, float s, bool pred) {
#pragma unroll
  for (int k = 0; k < 8; ++k) {
    int lo2 = k & ((1<<TB)-1);
    int j0 = ((k >> TB) << (TB+1)) | lo2;
    int j1 = j0 | (1<<TB);
    float a0r=sr[j0],a0i=si[j0],a1r=sr[j1],a1i=si[j1];
    float n0r = c*a0r + s*a1i, n0i = c*a0i - s*a1r;
    float n1r = c*a1r + s*a0i, n1i = c*a1i - s*a0r;
    sr[j0] = pred ? n0r : a0r; si[j0] = pred ? n0i : a0i;
    sr[j1] = pred ? n1r : a1r; si[j1] = pred ? n1i : a1i;
  }
}

template<int CB, int LB>
__device__ __forceinline__ void crx_reg_lane(float* sr, float* si, float c, float s) {
#pragma unroll
  for (int k = 0; k < 8; ++k) {
    int lo2 = k & ((1<<CB)-1);
    int j = ((((k >> CB) << (CB+1)) | lo2)) | (1<<CB);
    float pr = __shfl_xor(sr[j], 1<<LB, 64);
    float pi = __shfl_xor(si[j], 1<<LB, 64);
    float mr = sr[j], mi = si[j];
    sr[j] = c*mr + s*pi;
    si[j] = c*mi - s*pr;
  }
}

template<int LB>
__device__ __forceinline__ void crx_pred_lane(float* sr, float* si, float c, float s, bool pred) {
#pragma unroll
  for (int j = 0; j < 16; ++j) {
    float pr = __shfl_xor(sr[j], 1<<LB, 64);
    float pi = __shfl_xor(si[j], 1<<LB, 64);
    float mr = sr[j], mi = si[j];
    sr[j] = pred ? (c*mr + s*pi) : mr;
    si[j] = pred ? (c*mi - s*pr) : mi;
  }
}

// ---------------- LDS swizzled addressing (13-bit tile offset o -> float2 slot) ----------------
// row = o>>4 (512 rows of 16 float2). Column pairs XOR-swizzled by s(row) so that both
// row-varying and column-varying wave access patterns stay spread across banks.

__device__ __forceinline__ int swz_s(int row) { return (row ^ (row >> 3) ^ (row >> 6)) & 7; }
__device__ __forceinline__ int lds_addr(int o) {
  int row = o >> 4, c = o & 15;
  return row*16 + ((((c >> 1) + swz_s(row)) & 7) * 2) + (c & 1);
}

// ---------------- prep: fused U = Rot(w[q]) * RX(x[b,q]); CRX trig; zero feats ----------------

__global__ void kprep(const float* __restrict__ x, const float* __restrict__ w0,
                      const float* __restrict__ x0, const float* __restrict__ w1,
                      const float* __restrict__ x1, float* __restrict__ Us,
                      float* __restrict__ crx, float* __restrict__ feats) {
  int b = blockIdx.x;
  int t = threadIdx.x;
  if (t < 16) feats[b*16 + t] = 0.f;
  if (t < 32) {
    int l = t >> 4, q = t & 15;
    const float* W = (l ? w1 : w0) + q*3;
    float xa = 0.5f * x[b*16 + q];
    float cr = cosf(xa), sx = sinf(xa);
    float phi = W[0], th = W[1], om = W[2];
    float ct = cosf(0.5f*th), stt = sinf(0.5f*th);
    float po = 0.5f*(phi+om), pm = 0.5f*(phi-om);
    float ar =  cosf(po)*ct,  ai = -sinf(po)*ct;
    float br = -cosf(pm)*stt, bi = -sinf(pm)*stt;
    float cr2 = cosf(pm)*stt, ci2 = -sinf(pm)*stt;
    float dr =  cosf(po)*ct,  di =  sinf(po)*ct;
    float* U = Us + ((size_t)(b*2 + l)*16 + q)*8;
    U[0] = ar*cr + bi*sx;   U[1] = ai*cr - br*sx;
    U[2] = ai*sx + br*cr;   U[3] = -ar*sx + bi*cr;
    U[4] = cr2*cr + di*sx;  U[5] = ci2*cr - dr*sx;
    U[6] = ci2*sx + dr*cr;  U[7] = -cr2*sx + di*cr;
    if (b == 0) {
      float ang = 0.5f * (l ? x1[q] : x0[q]);
      crx[(l*16 + q)*2 + 0] = cosf(ang);
      crx[(l*16 + q)*2 + 1] = sinf(ang);
    }
  }
}

// ---------------- P12: layer0 + layer1 head, one state write ----------------
// Stage MA1 (compact j = global_idx>>3, support bits0..2=0; all 8 m-blocks per batch
//   compute identically): reg r0..3 = j9..j12; lane l0..5 = j3..j8; wv = j0..j2.
// Stage MB1: reg = j0..j3; lane = j4..j9; wv = j10..j12.
// Stage MA2 (global tile, block bits m = pos4,5,6): reg = pos0..3; lane l0..5 = pos10..15; wv = pos7,8,9.
// Stage MB2: reg = pos0..3; lane l0..2 = pos7,8,9; lane l3..5 = pos13,14,15; wv = pos10,11,12.

__global__ __launch_bounds__(512) void p12(float2* __restrict__ st, const float* __restrict__ Us,
                                           const float* __restrict__ crx) {
  __shared__ float2 lds2[8192];                    // 64 KB
  float4* lds4 = (float4*)lds2;
  int blk = blockIdx.x;
  int b = blk >> 3, m = blk & 7;
  int t = threadIdx.x, lane = t & 63, wv = t >> 6;
  const float* U0  = Us + (size_t)(b*2 + 0)*128;
  const float* U1  = Us + (size_t)(b*2 + 1)*128;
  const float* cx0 = crx;
  const float* cx1 = crx + 32;

  float sr[16], si[16];
#pragma unroll
  for (int r = 0; r < 16; ++r) { sr[r] = 0.f; si[r] = 0.f; }
  if (t == 0) sr[0] = 1.f;                         // |0...0>  (j=0)

  // ---- MA1: layer0 1q wires 0..9, CRX w0..8 ----
  g1q_reg<3>(sr,si,U0+0);          // wire0  (j12)
  g1q_reg<2>(sr,si,U0+8);          // wire1
  g1q_reg<1>(sr,si,U0+16);         // wire2
  g1q_reg<0>(sr,si,U0+24);         // wire3  (j9)
  g1q_lane<5>(sr,si,U0+32,lane);   // wire4  (j8)
  g1q_lane<4>(sr,si,U0+40,lane);   // wire5
  g1q_lane<3>(sr,si,U0+48,lane);   // wire6
  g1q_lane<2>(sr,si,U0+56,lane);   // wire7
  g1q_lane<1>(sr,si,U0+64,lane);   // wire8
  g1q_lane<0>(sr,si,U0+72,lane);   // wire9  (j3)
  crx_reg_reg<3,2>(sr,si,cx0[0],cx0[1]);                 // w0 (j12,j11)
  crx_reg_reg<2,1>(sr,si,cx0[2],cx0[3]);                 // w1
  crx_reg_reg<1,0>(sr,si,cx0[4],cx0[5]);                 // w2
  crx_reg_lane<0,5>(sr,si,cx0[6],cx0[7]);                // w3 (j9 -> j8)
  crx_pred_lane<4>(sr,si,cx0[8],cx0[9],(lane&32)!=0);    // w4
  crx_pred_lane<3>(sr,si,cx0[10],cx0[11],(lane&16)!=0);  // w5
  crx_pred_lane<2>(sr,si,cx0[12],cx0[13],(lane&8)!=0);   // w6
  crx_pred_lane<1>(sr,si,cx0[14],cx0[15],(lane&4)!=0);   // w7
  crx_pred_lane<0>(sr,si,cx0[16],cx0[17],(lane&2)!=0);   // w8 (j4 -> j3)

  // ---- remap#1: MA1 -> MB1 (o = j) ----
  {
    int base = wv | (lane << 3);
#pragma unroll
    for (int r = 0; r < 16; ++r)
      lds2[lds_addr(base | (r << 9))] = make_float2(sr[r], si[r]);
  }
  __syncthreads();
  {
    int row = lane | (wv << 6);
    int s = swz_s(row);
#pragma unroll
    for (int g = 0; g < 8; ++g) {
      float4 v = lds4[row*8 + ((g + s) & 7)];
      sr[2*g] = v.x; si[2*g] = v.y; sr[2*g+1] = v.z; si[2*g+1] = v.w;
    }
  }

  // ---- MB1: layer0 1q wires 10..12, CRX w9..11 ----
  g1q_reg<2>(sr,si,U0+80);         // wire10 (j2)
  g1q_reg<1>(sr,si,U0+88);         // wire11
  g1q_reg<0>(sr,si,U0+96);         // wire12 (j0)
  crx_reg_reg<3,2>(sr,si,cx0[18],cx0[19]);               // w9  (j3,j2)
  crx_reg_reg<2,1>(sr,si,cx0[20],cx0[21]);               // w10
  crx_reg_reg<1,0>(sr,si,cx0[22],cx0[23]);               // w11

  // ---- remap#2: keep slice pos4,5,6 == m; expand to global tile (o2 coords) ----
  // o2: bits0..3 = pos0..3; bits4..6 = pos7,8,9; bits7..12 = pos10..15
  __syncthreads();
  {
    int keep = m << 1;                               // r' = keep, keep+1 (j0 = r'&1 -> pos3)
    int base = ((lane & 7) << 4) | ((lane >> 3) << 7) | (wv << 10);
    lds2[lds_addr(base)]     = make_float2(sr[keep],   si[keep]);
    lds2[lds_addr(base | 8)] = make_float2(sr[keep+1], si[keep+1]);
  }
  __syncthreads();
  {
    int base = (wv << 4) | (lane << 7);
    float2 v0 = lds2[lds_addr(base)];
    float2 v8 = lds2[lds_addr(base | 8)];
#pragma unroll
    for (int r = 0; r < 16; ++r) { sr[r] = 0.f; si[r] = 0.f; }
    sr[0] = v0.x; si[0] = v0.y; sr[8] = v8.x; si[8] = v8.y;
  }

  // ---- MA2: layer0 tail + layer1 head ----
  g1q_reg<2>(sr,si,U0+104);        // wire13 (pos2)
  g1q_reg<1>(sr,si,U0+112);        // wire14
  g1q_reg<0>(sr,si,U0+120);        // wire15 (pos0)
  crx_reg_reg<3,2>(sr,si,cx0[24],cx0[25]);               // w12 (pos3,pos2)
  crx_reg_reg<2,1>(sr,si,cx0[26],cx0[27]);               // w13
  crx_reg_reg<1,0>(sr,si,cx0[28],cx0[29]);               // w14
  crx_reg_lane<0,5>(sr,si,cx0[30],cx0[31]);              // w15 (pos0 -> pos15)
  g1q_lane<5>(sr,si,U1+0,lane);    // L1 wire0 (pos15)
  g1q_lane<4>(sr,si,U1+8,lane);    // wire1
  g1q_lane<3>(sr,si,U1+16,lane);   // wire2
  g1q_lane<2>(sr,si,U1+24,lane);   // wire3
  g1q_lane<1>(sr,si,U1+32,lane);   // wire4
  g1q_lane<0>(sr,si,U1+40,lane);   // wire5 (pos10)
  g1q_reg<3>(sr,si,U1+96);         // wire12 (pos3)
  g1q_reg<2>(sr,si,U1+104);        // wire13
  g1q_reg<1>(sr,si,U1+112);        // wire14
  g1q_reg<0>(sr,si,U1+120);        // wire15 (pos0)
  crx_pred_lane<4>(sr,si,cx1[0],cx1[1],(lane&32)!=0);    // L1 w0
  crx_pred_lane<3>(sr,si,cx1[2],cx1[3],(lane&16)!=0);    // w1
  crx_pred_lane<2>(sr,si,cx1[4],cx1[5],(lane&8)!=0);     // w2
  crx_pred_lane<1>(sr,si,cx1[6],cx1[7],(lane&4)!=0);     // w3
  crx_pred_lane<0>(sr,si,cx1[8],cx1[9],(lane&2)!=0);     // w4

  // ---- remap#3: MA2 -> MB2 ----
  __syncthreads();
  {
    int row = wv | (lane << 3);                     // o2 = r | (wv<<4) | (lane<<7)
    int s = swz_s(row);
#pragma unroll
    for (int g = 0; g < 8; ++g)
      lds4[row*8 + ((g + s) & 7)] = make_float4(sr[2*g], si[2*g], sr[2*g+1], si[2*g+1]);
  }
  __syncthreads();
  {
    int row = (lane & 7) | (wv << 3) | ((lane >> 3) << 6);   // o2 = r | ((lane&7)<<4) | (wv<<7) | ((lane>>3)<<10)
    int s = swz_s(row);
#pragma unroll
    for (int g = 0; g < 8; ++g) {
      float4 v = lds4[row*8 + ((g + s) & 7)];
      sr[2*g] = v.x; si[2*g] = v.y; sr[2*g+1] = v.z; si[2*g+1] = v.w;
    }
  }

  // ---- MB2: layer1 1q wires 6..8, CRX w5..7 ----
  g1q_lane<2>(sr,si,U1+48,lane);   // wire6 (pos9 = lane2)
  g1q_lane<1>(sr,si,U1+56,lane);   // wire7
  g1q_lane<0>(sr,si,U1+64,lane);   // wire8 (pos7 = lane0)
  crx_pred_lane<2>(sr,si,cx1[10],cx1[11],(wv&1)!=0);     // w5 (ctrl pos10=wv0)
  crx_pred_lane<1>(sr,si,cx1[12],cx1[13],(lane&4)!=0);   // w6 (ctrl pos9=lane2)
  crx_pred_lane<0>(sr,si,cx1[14],cx1[15],(lane&2)!=0);   // w7 (ctrl pos8=lane1)

  // ---- store (natural layout, 128 B contiguous per thread) ----
  {
    size_t base = (size_t)b*DIM + (m<<4) + ((lane&7)<<7) + (wv<<10) + ((size_t)(lane>>3)<<13);
    float4* dst = (float4*)(st + base);
#pragma unroll
    for (int g = 0; g < 8; ++g)
      dst[g] = make_float4(sr[2*g], si[2*g], sr[2*g+1], si[2*g+1]);
  }
}

// ---------------- P3: layer1 tail + |amp|^2 + PauliZ signed sums ----------------
// Mapping: reg = pos0..3; lane l0,1,2 = pos4,5,6; l3,4 = pos8,9; l5 = pos15;
//          wv0 = pos7; wv1,2 = pos10,11; block m = pos12,13,14.

__global__ __launch_bounds__(512) void p3(const float2* __restrict__ st, const float* __restrict__ Us,
                                          const float* __restrict__ crx, float* __restrict__ feats) {
  int blk = blockIdx.x;
  int b = blk >> 3, m = blk & 7;
  int t = threadIdx.x, lane = t & 63, wv = t >> 6;
  const float* U1  = Us + (size_t)(b*2 + 1)*128;
  const float* cx1 = crx + 32;
  int idx0 = ((lane&7)<<4) | ((wv&1)<<7) | (((lane>>3)&3)<<8) | ((wv>>1)<<10) | (m<<12) | ((lane>>5)<<15);
  const float4* src = (const float4*)(st + (size_t)b*DIM + idx0);
  float sr[16], si[16];
#pragma unroll
  for (int g = 0; g < 8; ++g) {
    float4 v = src[g];
    sr[2*g] = v.x; si[2*g] = v.y; sr[2*g+1] = v.z; si[2*g+1] = v.w;
  }
  g1q_lane<2>(sr,si,U1+72,lane);   // wire9  (pos6 = lane2)
  g1q_lane<1>(sr,si,U1+80,lane);   // wire10 (pos5)
  g1q_lane<0>(sr,si,U1+88,lane);   // wire11 (pos4)
  crx_pred_lane<2>(sr,si,cx1[16],cx1[17],(wv&1)!=0);     // w8  (ctrl pos7=wv0, tgt pos6)
  crx_pred_lane<1>(sr,si,cx1[18],cx1[19],(lane&4)!=0);   // w9  (ctrl pos6, tgt pos5)
  crx_pred_lane<0>(sr,si,cx1[20],cx1[21],(lane&2)!=0);   // w10 (ctrl pos5, tgt pos4)
  crx_pred_reg<3>(sr,si,cx1[22],cx1[23],(lane&1)!=0);    // w11 (ctrl pos4=lane0, tgt pos3=reg3)
  crx_reg_reg<3,2>(sr,si,cx1[24],cx1[25]);               // w12
  crx_reg_reg<2,1>(sr,si,cx1[26],cx1[27]);               // w13
  crx_reg_reg<1,0>(sr,si,cx1[28],cx1[29]);               // w14
  crx_reg_lane<0,5>(sr,si,cx1[30],cx1[31]);              // w15 (ctrl pos0=reg0, tgt pos15=lane5)

  float tot=0.f, sA=0.f, sB=0.f, sC=0.f, sD=0.f;
#pragma unroll
  for (int r = 0; r < 16; ++r) {
    float p = sr[r]*sr[r] + si[r]*si[r];
    tot += p;
    sA += (r & 1) ? -p : p;   // pos0 -> wire15
    sB += (r & 2) ? -p : p;   // pos1 -> wire14
    sC += (r & 4) ? -p : p;   // pos2 -> wire13
    sD += (r & 8) ? -p : p;   // pos3 -> wire12
  }
  float f[16];
  f[15] = sA; f[14] = sB; f[13] = sC; f[12] = sD;
  f[11] = (lane&1)  ? -tot : tot;   // pos4
  f[10] = (lane&2)  ? -tot : tot;   // pos5
  f[9]  = (lane&4)  ? -tot : tot;   // pos6
  f[7]  = (lane&8)  ? -tot : tot;   // pos8
  f[6]  = (lane&16) ? -tot : tot;   // pos9
  f[0]  = (lane&32) ? -tot : tot;   // pos15
  f[8]  = (wv&1)    ? -tot : tot;   // pos7
  f[5]  = (wv&2)    ? -tot : tot;   // pos10
  f[4]  = (wv&4)    ? -tot : tot;   // pos11
  f[3]  = (m&1)     ? -tot : tot;   // pos12
  f[2]  = (m&2)     ? -tot : tot;   // pos13
  f[1]  = (m&4)     ? -tot : tot;   // pos14
#pragma unroll
  for (int w = 0; w < 16; ++w) {
#pragma unroll
    for (int off = 32; off; off >>= 1) f[w] += __shfl_xor(f[w], off, 64);
  }
  __shared__ float red[8][17];
  if (lane == 0) {
#pragma unroll
    for (int w = 0; w < 16; ++w) red[wv][w] = f[w];
  }
  __syncthreads();
  if (t < 16) {
    float acc = 0.f;
#pragma unroll
    for (int i = 0; i < 8; ++i) acc += red[i][t];
    atomicAdd(&feats[b*16 + t], acc);
  }
}

// ---------------- FC + log_softmax ----------------

__global__ void kfc(const float* __restrict__ feats, const float* __restrict__ fcw,
                    const float* __restrict__ fcb, float* __restrict__ out) {
  int b = blockIdx.x, t = threadIdx.x;
  __shared__ float fs[16];
  __shared__ float lg[23];
  if (t < 16) fs[t] = feats[b*16 + t];
  __syncthreads();
  if (t < 23) {
    float acc = fcb[t];
#pragma unroll
    for (int w = 0; w < 16; ++w) acc += fs[w] * fcw[t*16 + w];
    lg[t] = acc;
  }
  __syncthreads();
  if (t < 23) {
    float mx = -1e30f;
#pragma unroll
    for (int j = 0; j < 23; ++j) mx = fmaxf(mx, lg[j]);
    float Ssum = 0.f;
#pragma unroll
    for (int j = 0; j < 23; ++j) Ssum += expf(lg[j] - mx);
    out[b*23 + t] = lg[t] - mx - logf(Ssum);
  }
}

extern "C" void kernel_launch(void* const* d_in, const int* in_sizes, int n_in,
                              void* d_out, int out_size, void* d_ws, size_t ws_size,
                              hipStream_t stream) {
  const float* x   = (const float*)d_in[0];
  const float* w0  = (const float*)d_in[1];
  const float* x0  = (const float*)d_in[2];
  const float* w1  = (const float*)d_in[3];
  const float* x1  = (const float*)d_in[4];
  const float* fcw = (const float*)d_in[5];
  const float* fcb = (const float*)d_in[6];
  float* out = (float*)d_out;

  char* ws = (char*)d_ws;
  float2* st  = (float2*)ws;                                         // 32 MB
  float*  Us  = (float*)(ws + (size_t)BATCH * DIM * sizeof(float2)); // 64 KB
  float*  crx = Us + (size_t)BATCH*2*16*8;                           // 64 f32
  float*  feats = crx + 64;                                          // 1 KB

  kprep<<<BATCH, 64, 0, stream>>>(x, w0, x0, w1, x1, Us, crx, feats);
  p12<<<512, 512, 0, stream>>>(st, Us, crx);
  p3 <<<512, 512, 0, stream>>>(st, Us, crx, feats);
  kfc<<<BATCH, 32, 0, stream>>>(feats, fcw, fcb, out);
  (void)in_sizes; (void)n_in; (void)out_size; (void)ws_size;
}

// Round 4
// 141.706 us; speedup vs baseline: 1.3188x; 1.2083x over previous
//
#include <hip/hip_runtime.h>
#include <hip/hip_bf16.h>

// 16-qubit statevector sim, batch 64. idx bit p ("pos p") = bit p of state index; wire w <-> pos 15-w.
// CRX fusion: CRX(ctrl,tgt)*U(tgt) = ctrl-selected 1q gate {M0=U, M1=RX*U} (within-layer: CRX after F).
// Layer-boundary gate (L1 w0 fused with L0 CRX(15->0)): CRX BEFORE F -> M1 = U*RX (right-mult!).
// Pipeline:
//   kprep: fused U (M0) + M1 per (b,layer,wire); T0/T1 tables (L0 w13..15 + CRX w12..14); crx15.
//   pA (64 blk): L0 compact 13-bit stage (1q w0..12 + CRX w0..11 fused), once per batch -> cst (4 MB).
//   pB (512 blk): T-expand (+CRX w12..14, 1q w13..15), Gx=(L0 CRX w15 + L1 1q w0), G0..G7, store st.
//   p3 (512 blk): G8..G14, CRX w15 (L1), |amp|^2 + PauliZ sums -> feats.
//   kfc: FC + log_softmax.

#define NQ 16
#define DIM 65536
#define BATCH 64
#define PSTR 544   // floats per batch in P: 2*16*2*8 = 512 matrices + 16 T0 + 16 T1

// ---------------- gate helpers ----------------

// plain 1q on register bit RB
template<int RB>
__device__ __forceinline__ void g1q_reg(float* sr, float* si, const float* U) {
  float u00r=U[0],u00i=U[1],u01r=U[2],u01i=U[3],u10r=U[4],u10i=U[5],u11r=U[6],u11i=U[7];
#pragma unroll
  for (int k = 0; k < 8; ++k) {
    int lo = k & ((1<<RB)-1);
    int j0 = ((k >> RB) << (RB+1)) | lo;
    int j1 = j0 | (1<<RB);
    float a0r=sr[j0], a0i=si[j0], a1r=sr[j1], a1i=si[j1];
    sr[j0] = u00r*a0r - u00i*a0i + u01r*a1r - u01i*a1i;
    si[j0] = u00r*a0i + u00i*a0r + u01r*a1i + u01i*a1r;
    sr[j1] = u10r*a0r - u10i*a0i + u11r*a1r - u11i*a1i;
    si[j1] = u10r*a0i + u10i*a0r + u11r*a1i + u11i*a1r;
  }
}

// fused gate, target lane bit LB, ctrl = runtime predicate (lane/wv bit)
template<int LB>
__device__ __forceinline__ void gsel_lane(float* sr, float* si, const float* M0, const float* M1,
                                          int lane, bool ctrl) {
  int side = (lane >> LB) & 1;
  float d0r = side ? M0[6] : M0[0], d0i = side ? M0[7] : M0[1];
  float o0r = side ? M0[4] : M0[2], o0i = side ? M0[5] : M0[3];
  float d1r = side ? M1[6] : M1[0], d1i = side ? M1[7] : M1[1];
  float o1r = side ? M1[4] : M1[2], o1i = side ? M1[5] : M1[3];
  float dr = ctrl ? d1r : d0r, di = ctrl ? d1i : d0i;
  float og = ctrl ? o1r : o0r, oi = ctrl ? o1i : o0i;
#pragma unroll
  for (int j = 0; j < 16; ++j) {
    float pr = __shfl_xor(sr[j], 1<<LB, 64);
    float pi = __shfl_xor(si[j], 1<<LB, 64);
    float mr = sr[j], mi = si[j];
    sr[j] = dr*mr - di*mi + og*pr - oi*pi;
    si[j] = dr*mi + di*mr + og*pi + oi*pr;
  }
}

// fused gate, target lane bit LB, ctrl = reg bit CB (compile-time per amp)
template<int LB, int CB>
__device__ __forceinline__ void gsel_lane_creg(float* sr, float* si, const float* M0,
                                               const float* M1, int lane) {
  int side = (lane >> LB) & 1;
  float d0r = side ? M0[6] : M0[0], d0i = side ? M0[7] : M0[1];
  float o0r = side ? M0[4] : M0[2], o0i = side ? M0[5] : M0[3];
  float d1r = side ? M1[6] : M1[0], d1i = side ? M1[7] : M1[1];
  float o1r = side ? M1[4] : M1[2], o1i = side ? M1[5] : M1[3];
#pragma unroll
  for (int j = 0; j < 16; ++j) {
    const bool c = ((j >> CB) & 1) != 0;
    float dr = c ? d1r : d0r, di = c ? d1i : d0i;
    float og = c ? o1r : o0r, oi = c ? o1i : o0i;
    float pr = __shfl_xor(sr[j], 1<<LB, 64);
    float pi = __shfl_xor(si[j], 1<<LB, 64);
    float mr = sr[j], mi = si[j];
    sr[j] = dr*mr - di*mi + og*pr - oi*pi;
    si[j] = dr*mi + di*mr + og*pi + oi*pr;
  }
}

// fused gate, target reg bit RB, ctrl = reg bit CB (compile-time per pair)
template<int RB, int CB>
__device__ __forceinline__ void gsel_reg_cc(float* sr, float* si, const float* M0, const float* M1) {
  float a0=M0[0],a1=M0[1],a2=M0[2],a3=M0[3],a4=M0[4],a5=M0[5],a6=M0[6],a7=M0[7];
  float b0=M1[0],b1=M1[1],b2=M1[2],b3=M1[3],b4=M1[4],b5=M1[5],b6=M1[6],b7=M1[7];
#pragma unroll
  for (int k = 0; k < 8; ++k) {
    int lo = k & ((1<<RB)-1);
    int j0 = ((k >> RB) << (RB+1)) | lo;
    int j1 = j0 | (1<<RB);
    const bool c = ((j0 >> CB) & 1) != 0;
    float u00r=c?b0:a0, u00i=c?b1:a1, u01r=c?b2:a2, u01i=c?b3:a3;
    float u10r=c?b4:a4, u10i=c?b5:a5, u11r=c?b6:a6, u11i=c?b7:a7;
    float p0r=sr[j0], p0i=si[j0], p1r=sr[j1], p1i=si[j1];
    sr[j0] = u00r*p0r - u00i*p0i + u01r*p1r - u01i*p1i;
    si[j0] = u00r*p0i + u00i*p0r + u01r*p1i + u01i*p1r;
    sr[j1] = u10r*p0r - u10i*p0i + u11r*p1r - u11i*p1i;
    si[j1] = u10r*p0i + u10i*p0r + u11r*p1i + u11i*p1r;
  }
}

// fused gate, target reg bit RB, ctrl = runtime predicate
template<int RB>
__device__ __forceinline__ void gsel_reg_pred(float* sr, float* si, const float* M0,
                                              const float* M1, bool ctrl) {
  float u[8];
#pragma unroll
  for (int e = 0; e < 8; ++e) u[e] = ctrl ? M1[e] : M0[e];
  g1q_reg<RB>(sr, si, u);
}

// standalone CRX: ctrl reg bit CB, target lane bit LB
template<int CB, int LB>
__device__ __forceinline__ void crx_reg_lane(float* sr, float* si, float c, float s) {
#pragma unroll
  for (int k = 0; k < 8; ++k) {
    int lo2 = k & ((1<<CB)-1);
    int j = ((((k >> CB) << (CB+1)) | lo2)) | (1<<CB);
    float pr = __shfl_xor(sr[j], 1<<LB, 64);
    float pi = __shfl_xor(si[j], 1<<LB, 64);
    float mr = sr[j], mi = si[j];
    sr[j] = c*mr + s*pi;
    si[j] = c*mi - s*pr;
  }
}

// ---------------- LDS swizzled addressing ----------------
__device__ __forceinline__ int swz_s(int row) { return (row ^ (row >> 3) ^ (row >> 6)) & 7; }
__device__ __forceinline__ int lds_addr(int o) {
  int row = o >> 4, c = o & 15;
  return row*16 + ((((c >> 1) + swz_s(row)) & 7) * 2) + (c & 1);
}

// ---------------- kprep ----------------
// P layout per batch: M(l,q,s) at ((l*16+q)*2+s)*8. s=0: U = Rot*RX (fused 1q). s=1:
//   q>=1: RX(xc[l][q-1]) * U   (within-layer: CRX after F)
//   q==0: U * RX(prev-layer crx15 angle)  (layer boundary: CRX BEFORE F)
// T0 at 512, T1 at 528.

__global__ void kprep(const float* __restrict__ x, const float* __restrict__ w0,
                      const float* __restrict__ x0, const float* __restrict__ w1,
                      const float* __restrict__ x1, float* __restrict__ P,
                      float* __restrict__ crxb, float* __restrict__ feats) {
  __shared__ float su[32][8];
  int b = blockIdx.x;
  int t = threadIdx.x;
  if (t < 16) feats[b*16 + t] = 0.f;
  if (t < 32) {
    int l = t >> 4, q = t & 15;
    const float* W = (l ? w1 : w0) + q*3;
    float xa = 0.5f * x[b*16 + q];
    float cr = cosf(xa), sx = sinf(xa);
    float phi = W[0], th = W[1], om = W[2];
    float ct = cosf(0.5f*th), stt = sinf(0.5f*th);
    float po = 0.5f*(phi+om), pm = 0.5f*(phi-om);
    float ar =  cosf(po)*ct,  ai = -sinf(po)*ct;
    float br = -cosf(pm)*stt, bi = -sinf(pm)*stt;
    float cr2 = cosf(pm)*stt, ci2 = -sinf(pm)*stt;
    float dr =  cosf(po)*ct,  di =  sinf(po)*ct;
    float U[8];
    U[0] = ar*cr + bi*sx;   U[1] = ai*cr - br*sx;
    U[2] = ai*sx + br*cr;   U[3] = -ar*sx + bi*cr;
    U[4] = cr2*cr + di*sx;  U[5] = ci2*cr - dr*sx;
    U[6] = ci2*sx + dr*cr;  U[7] = -cr2*sx + di*cr;
    float* M0 = P + (size_t)b*PSTR + ((l*16+q)*2+0)*8;
    float* M1 = M0 + 8;
#pragma unroll
    for (int e = 0; e < 8; ++e) { M0[e] = U[e]; su[t][e] = U[e]; }
    if (q == 0) {
      // layer boundary: M1 = U * RX(ang), ang = prev layer's crx15 half-angle (l=0: none -> 0)
      float ang = l ? 0.5f*x0[15] : 0.f;
      float cg = cosf(ang), sg = sinf(ang);
      M1[0] =  cg*U[0] + sg*U[3];  M1[1] = cg*U[1] - sg*U[2];
      M1[2] =  sg*U[1] + cg*U[2];  M1[3] = -sg*U[0] + cg*U[3];
      M1[4] =  cg*U[4] + sg*U[7];  M1[5] = cg*U[5] - sg*U[6];
      M1[6] =  sg*U[5] + cg*U[6];  M1[7] = -sg*U[4] + cg*U[7];
    } else {
      // within layer: M1 = RX(ang) * U
      float ang = 0.5f*(l ? x1[q-1] : x0[q-1]);
      float cg = cosf(ang), sg = sinf(ang);
      M1[0] = cg*U[0] + sg*U[5];  M1[1] = cg*U[1] - sg*U[4];
      M1[2] = cg*U[2] + sg*U[7];  M1[3] = cg*U[3] - sg*U[6];
      M1[4] = cg*U[4] + sg*U[1];  M1[5] = cg*U[5] - sg*U[0];
      M1[6] = cg*U[6] + sg*U[3];  M1[7] = cg*U[7] - sg*U[2];
    }
    if (b == 0 && t == 0) { crxb[0] = cosf(0.5f*x1[15]); crxb[1] = sinf(0.5f*x1[15]); }
  }
  __syncthreads();
  if (t == 0) {
    // T tables: L0 1q w13,14,15 from |000> (column-0 products), then CRX w12 (branch), w13, w14.
    float T0r[8], T0i[8], T1r[8], T1i[8];
#pragma unroll
    for (int k = 0; k < 8; ++k) {
      int b2 = (k>>2)&1, b1 = (k>>1)&1, b0k = k&1;
      float xr = su[13][b2*4], xi = su[13][b2*4+1];
      float yr = su[14][b1*4], yi = su[14][b1*4+1];
      float zr = su[15][b0k*4], zi = su[15][b0k*4+1];
      float pr = xr*yr - xi*yi, pi = xr*yi + xi*yr;
      T0r[k] = pr*zr - pi*zi; T0i[k] = pr*zi + pi*zr;
    }
    float a12 = 0.5f*x0[12], c12 = cosf(a12), s12 = sinf(a12);
#pragma unroll
    for (int k = 0; k < 8; ++k) { T1r[k] = c12*T0r[k] + s12*T0i[k^4]; T1i[k] = c12*T0i[k] - s12*T0r[k^4]; }
    float a13 = 0.5f*x0[13], c13 = cosf(a13), s13 = sinf(a13);
    float n0r[8], n0i[8], n1r[8], n1i[8];
#pragma unroll
    for (int k = 0; k < 8; ++k) {
      if (k & 4) {
        n0r[k] = c13*T0r[k] + s13*T0i[k^2]; n0i[k] = c13*T0i[k] - s13*T0r[k^2];
        n1r[k] = c13*T1r[k] + s13*T1i[k^2]; n1i[k] = c13*T1i[k] - s13*T1r[k^2];
      } else { n0r[k]=T0r[k]; n0i[k]=T0i[k]; n1r[k]=T1r[k]; n1i[k]=T1i[k]; }
    }
    float a14 = 0.5f*x0[14], c14 = cosf(a14), s14 = sinf(a14);
    float* T0 = P + (size_t)b*PSTR + 512;
    float* T1 = T0 + 16;
#pragma unroll
    for (int k = 0; k < 8; ++k) {
      float r0, i0, r1, i1;
      if (k & 2) {
        r0 = c14*n0r[k] + s14*n0i[k^1]; i0 = c14*n0i[k] - s14*n0r[k^1];
        r1 = c14*n1r[k] + s14*n1i[k^1]; i1 = c14*n1i[k] - s14*n1r[k^1];
      } else { r0=n0r[k]; i0=n0i[k]; r1=n1r[k]; i1=n1i[k]; }
      T0[2*k] = r0; T0[2*k+1] = i0; T1[2*k] = r1; T1[2*k+1] = i1;
    }
  }
}

#define MP(Pb, l, q, s) ((Pb) + (((l)*16+(q))*2+(s))*8)

// ---------------- pA: L0 compact 13-bit stage, once per batch ----------------
// MA1: reg r0..3 = j9..j12; lane l0..5 = j3..j8; wv = j0..j2.
// MB1: reg = j0..j3; lane = j4..j9; wv = j10..j12.
// cst float4 index: [b][ j1..3 ][ (j4..6) | (j7..9)<<3 | (j10..12)<<6 ]; float4 = (j0=0, j0=1) pair.

__global__ __launch_bounds__(512) void pA(float4* __restrict__ cst4, const float* __restrict__ P) {
  __shared__ float2 lds2[8192];
  float4* lds4 = (float4*)lds2;
  int b = blockIdx.x;
  int t = threadIdx.x, lane = t & 63, wv = t >> 6;
  const float* Pb = P + (size_t)b*PSTR;

  float sr[16], si[16];
#pragma unroll
  for (int r = 0; r < 16; ++r) { sr[r] = 0.f; si[r] = 0.f; }
  if (t == 0) sr[0] = 1.f;

  g1q_reg<3>(sr, si, MP(Pb,0,0,0));                                // 1q w0 (j12)
  gsel_reg_cc<2,3>(sr, si, MP(Pb,0,1,0), MP(Pb,0,1,1));            // G0: w1, ctrl w0
  gsel_reg_cc<1,2>(sr, si, MP(Pb,0,2,0), MP(Pb,0,2,1));            // G1
  gsel_reg_cc<0,1>(sr, si, MP(Pb,0,3,0), MP(Pb,0,3,1));            // G2
  gsel_lane_creg<5,0>(sr, si, MP(Pb,0,4,0), MP(Pb,0,4,1), lane);   // G3: w4(j8), ctrl w3(j9=reg0)
  gsel_lane<4>(sr, si, MP(Pb,0,5,0), MP(Pb,0,5,1), lane, (lane&32)!=0);  // G4
  gsel_lane<3>(sr, si, MP(Pb,0,6,0), MP(Pb,0,6,1), lane, (lane&16)!=0);  // G5
  gsel_lane<2>(sr, si, MP(Pb,0,7,0), MP(Pb,0,7,1), lane, (lane&8)!=0);   // G6
  gsel_lane<1>(sr, si, MP(Pb,0,8,0), MP(Pb,0,8,1), lane, (lane&4)!=0);   // G7
  gsel_lane<0>(sr, si, MP(Pb,0,9,0), MP(Pb,0,9,1), lane, (lane&2)!=0);   // G8: w9(j3), ctrl w8(j4)

  // remap: MA1 -> MB1
  {
    int base = wv | (lane << 3);
#pragma unroll
    for (int r = 0; r < 16; ++r)
      lds2[lds_addr(base | (r << 9))] = make_float2(sr[r], si[r]);
  }
  __syncthreads();
  {
    int row = lane | (wv << 6);
    int s = swz_s(row);
#pragma unroll
    for (int g = 0; g < 8; ++g) {
      float4 v = lds4[row*8 + ((g + s) & 7)];
      sr[2*g] = v.x; si[2*g] = v.y; sr[2*g+1] = v.z; si[2*g+1] = v.w;
    }
  }

  gsel_reg_cc<2,3>(sr, si, MP(Pb,0,10,0), MP(Pb,0,10,1));          // G9:  w10(j2), ctrl w9(j3)
  gsel_reg_cc<1,2>(sr, si, MP(Pb,0,11,0), MP(Pb,0,11,1));          // G10
  gsel_reg_cc<0,1>(sr, si, MP(Pb,0,12,0), MP(Pb,0,12,1));          // G11

  // store compact state
  {
    int f4 = (lane & 7) | (((lane >> 3) & 7) << 3) | (wv << 6);
#pragma unroll
    for (int m = 0; m < 8; ++m)
      cst4[(size_t)b*4096 + m*512 + f4] = make_float4(sr[2*m], si[2*m], sr[2*m+1], si[2*m+1]);
  }
}

// ---------------- pB: expand + Gx + L1 head, store state ----------------
// MA2: reg = pos0..3; lane l0..5 = pos10..15; wv = pos7,8,9; block m = pos4,5,6.
// MB2: reg = pos0..3; lane l0..2 = pos7,8,9; l3..5 = pos13,14,15; wv = pos10,11,12.

__global__ __launch_bounds__(512) void pB(float2* __restrict__ st, const float4* __restrict__ cst4,
                                          const float* __restrict__ P) {
  __shared__ float2 lds2[8192];
  float4* lds4 = (float4*)lds2;
  int blk = blockIdx.x;
  int b = blk >> 3, m = blk & 7;
  int t = threadIdx.x, lane = t & 63, wv = t >> 6;
  const float* Pb = P + (size_t)b*PSTR;

  // load compact pair, expand via T tables (absorbs L0 1q w13..15 + CRX w12..14)
  float sr[16], si[16];
  {
    float4 cc = cst4[(size_t)b*4096 + m*512 + (wv | ((lane & 7) << 3) | ((lane >> 3) << 6))];
    const float* T0 = Pb + 512;
    const float* T1 = Pb + 528;
#pragma unroll
    for (int r = 0; r < 16; ++r) {
      int k = r & 7;
      float tr = (r < 8) ? T0[2*k]   : T1[2*k];
      float ti = (r < 8) ? T0[2*k+1] : T1[2*k+1];
      float car = (r < 8) ? cc.x : cc.z;
      float cai = (r < 8) ? cc.y : cc.w;
      sr[r] = tr*car - ti*cai;
      si[r] = tr*cai + ti*car;
    }
  }

  gsel_lane_creg<5,0>(sr, si, MP(Pb,1,0,0), MP(Pb,1,0,1), lane);   // Gx: L1 w0 (pos15), ctrl pos0 (L0 CRX w15)
  gsel_lane<4>(sr, si, MP(Pb,1,1,0), MP(Pb,1,1,1), lane, (lane&32)!=0);  // G0: w1, ctrl pos15
  gsel_lane<3>(sr, si, MP(Pb,1,2,0), MP(Pb,1,2,1), lane, (lane&16)!=0);  // G1
  gsel_lane<2>(sr, si, MP(Pb,1,3,0), MP(Pb,1,3,1), lane, (lane&8)!=0);   // G2
  gsel_lane<1>(sr, si, MP(Pb,1,4,0), MP(Pb,1,4,1), lane, (lane&4)!=0);   // G3
  gsel_lane<0>(sr, si, MP(Pb,1,5,0), MP(Pb,1,5,1), lane, (lane&2)!=0);   // G4: w5(pos10), ctrl pos11

  // remap: MA2 -> MB2
  __syncthreads();
  {
    int row = wv | (lane << 3);
    int s = swz_s(row);
#pragma unroll
    for (int g = 0; g < 8; ++g)
      lds4[row*8 + ((g + s) & 7)] = make_float4(sr[2*g], si[2*g], sr[2*g+1], si[2*g+1]);
  }
  __syncthreads();
  {
    int row = (lane & 7) | (wv << 3) | ((lane >> 3) << 6);
    int s = swz_s(row);
#pragma unroll
    for (int g = 0; g < 8; ++g) {
      float4 v = lds4[row*8 + ((g + s) & 7)];
      sr[2*g] = v.x; si[2*g] = v.y; sr[2*g+1] = v.z; si[2*g+1] = v.w;
    }
  }

  gsel_lane<2>(sr, si, MP(Pb,1,6,0), MP(Pb,1,6,1), lane, (wv&1)!=0);     // G5: w6(pos9), ctrl pos10(wv0)
  gsel_lane<1>(sr, si, MP(Pb,1,7,0), MP(Pb,1,7,1), lane, (lane&4)!=0);   // G6: w7(pos8), ctrl pos9
  gsel_lane<0>(sr, si, MP(Pb,1,8,0), MP(Pb,1,8,1), lane, (lane&2)!=0);   // G7: w8(pos7), ctrl pos8

  // store (natural layout)
  {
    size_t base = (size_t)b*DIM + (m<<4) + ((lane&7)<<7) + (wv<<10) + ((size_t)(lane>>3)<<13);
    float4* dst = (float4*)(st + base);
#pragma unroll
    for (int g = 0; g < 8; ++g)
      dst[g] = make_float4(sr[2*g], si[2*g], sr[2*g+1], si[2*g+1]);
  }
}

// ---------------- p3: L1 tail + observables ----------------
// reg = pos0..3; lane l0,1,2 = pos4,5,6; l3,4 = pos8,9; l5 = pos15; wv0 = pos7; wv1,2 = pos10,11;
// block m = pos12,13,14.

__global__ __launch_bounds__(512) void p3(const float2* __restrict__ st, const float* __restrict__ P,
                                          const float* __restrict__ crxb, float* __restrict__ feats) {
  int blk = blockIdx.x;
  int b = blk >> 3, m = blk & 7;
  int t = threadIdx.x, lane = t & 63, wv = t >> 6;
  const float* Pb = P + (size_t)b*PSTR;
  int idx0 = ((lane&7)<<4) | ((wv&1)<<7) | (((lane>>3)&3)<<8) | ((wv>>1)<<10) | (m<<12) | ((lane>>5)<<15);
  const float4* src = (const float4*)(st + (size_t)b*DIM + idx0);
  float sr[16], si[16];
#pragma unroll
  for (int g = 0; g < 8; ++g) {
    float4 v = src[g];
    sr[2*g] = v.x; si[2*g] = v.y; sr[2*g+1] = v.z; si[2*g+1] = v.w;
  }
  gsel_lane<2>(sr, si, MP(Pb,1,9,0),  MP(Pb,1,9,1),  lane, (wv&1)!=0);   // G8:  w9(pos6), ctrl pos7(wv0)
  gsel_lane<1>(sr, si, MP(Pb,1,10,0), MP(Pb,1,10,1), lane, (lane&4)!=0); // G9:  w10(pos5), ctrl pos6
  gsel_lane<0>(sr, si, MP(Pb,1,11,0), MP(Pb,1,11,1), lane, (lane&2)!=0); // G10: w11(pos4), ctrl pos5
  gsel_reg_pred<3>(sr, si, MP(Pb,1,12,0), MP(Pb,1,12,1), (lane&1)!=0);   // G11: w12(pos3), ctrl pos4
  gsel_reg_cc<2,3>(sr, si, MP(Pb,1,13,0), MP(Pb,1,13,1));                // G12: w13(pos2), ctrl pos3
  gsel_reg_cc<1,2>(sr, si, MP(Pb,1,14,0), MP(Pb,1,14,1));                // G13
  gsel_reg_cc<0,1>(sr, si, MP(Pb,1,15,0), MP(Pb,1,15,1));                // G14: w15(pos0), ctrl pos1
  crx_reg_lane<0,5>(sr, si, crxb[0], crxb[1]);                           // L1 CRX w15: ctrl pos0, tgt pos15

  float tot=0.f, sA=0.f, sB=0.f, sC=0.f, sD=0.f;
#pragma unroll
  for (int r = 0; r < 16; ++r) {
    float p = sr[r]*sr[r] + si[r]*si[r];
    tot += p;
    sA += (r & 1) ? -p : p;   // pos0 -> wire15
    sB += (r & 2) ? -p : p;   // pos1 -> wire14
    sC += (r & 4) ? -p : p;   // pos2 -> wire13
    sD += (r & 8) ? -p : p;   // pos3 -> wire12
  }
  float f[16];
  f[15] = sA; f[14] = sB; f[13] = sC; f[12] = sD;
  f[11] = (lane&1)  ? -tot : tot;   // pos4
  f[10] = (lane&2)  ? -tot : tot;   // pos5
  f[9]  = (lane&4)  ? -tot : tot;   // pos6
  f[7]  = (lane&8)  ? -tot : tot;   // pos8
  f[6]  = (lane&16) ? -tot : tot;   // pos9
  f[0]  = (lane&32) ? -tot : tot;   // pos15
  f[8]  = (wv&1)    ? -tot : tot;   // pos7
  f[5]  = (wv&2)    ? -tot : tot;   // pos10
  f[4]  = (wv&4)    ? -tot : tot;   // pos11
  f[3]  = (m&1)     ? -tot : tot;   // pos12
  f[2]  = (m&2)     ? -tot : tot;   // pos13
  f[1]  = (m&4)     ? -tot : tot;   // pos14
#pragma unroll
  for (int w = 0; w < 16; ++w) {
#pragma unroll
    for (int off = 32; off; off >>= 1) f[w] += __shfl_xor(f[w], off, 64);
  }
  __shared__ float red[8][17];
  if (lane == 0) {
#pragma unroll
    for (int w = 0; w < 16; ++w) red[wv][w] = f[w];
  }
  __syncthreads();
  if (t < 16) {
    float acc = 0.f;
#pragma unroll
    for (int i = 0; i < 8; ++i) acc += red[i][t];
    atomicAdd(&feats[b*16 + t], acc);
  }
}

// ---------------- FC + log_softmax ----------------

__global__ void kfc(const float* __restrict__ feats, const float* __restrict__ fcw,
                    const float* __restrict__ fcb, float* __restrict__ out) {
  int b = blockIdx.x, t = threadIdx.x;
  __shared__ float fs[16];
  __shared__ float lg[23];
  if (t < 16) fs[t] = feats[b*16 + t];
  __syncthreads();
  if (t < 23) {
    float acc = fcb[t];
#pragma unroll
    for (int w = 0; w < 16; ++w) acc += fs[w] * fcw[t*16 + w];
    lg[t] = acc;
  }
  __syncthreads();
  if (t < 23) {
    float mx = -1e30f;
#pragma unroll
    for (int j = 0; j < 23; ++j) mx = fmaxf(mx, lg[j]);
    float Ssum = 0.f;
#pragma unroll
    for (int j = 0; j < 23; ++j) Ssum += expf(lg[j] - mx);
    out[b*23 + t] = lg[t] - mx - logf(Ssum);
  }
}

extern "C" void kernel_launch(void* const* d_in, const int* in_sizes, int n_in,
                              void* d_out, int out_size, void* d_ws, size_t ws_size,
                              hipStream_t stream) {
  const float* x   = (const float*)d_in[0];
  const float* w0  = (const float*)d_in[1];
  const float* x0  = (const float*)d_in[2];
  const float* w1  = (const float*)d_in[3];
  const float* x1  = (const float*)d_in[4];
  const float* fcw = (const float*)d_in[5];
  const float* fcb = (const float*)d_in[6];
  float* out = (float*)d_out;

  char* ws = (char*)d_ws;
  float2* st   = (float2*)ws;                                        // 32 MB
  float4* cst4 = (float4*)(ws + (size_t)BATCH * DIM * sizeof(float2));  // 4 MB
  float*  P    = (float*)((char*)cst4 + (size_t)BATCH * 8192 * sizeof(float2));  // 139 KB
  float*  crxb = P + (size_t)BATCH * PSTR;
  float*  feats = crxb + 16;

  kprep<<<BATCH, 64, 0, stream>>>(x, w0, x0, w1, x1, P, crxb, feats);
  pA<<<BATCH, 512, 0, stream>>>(cst4, P);
  pB<<<512, 512, 0, stream>>>(st, cst4, P);
  p3<<<512, 512, 0, stream>>>(st, P, crxb, feats);
  kfc<<<BATCH, 32, 0, stream>>>(feats, fcw, fcb, out);
  (void)in_sizes; (void)n_in; (void)out_size; (void)ws_size;
}

// Round 5
// 140.069 us; speedup vs baseline: 1.3342x; 1.0117x over previous
//
#include <hip/hip_runtime.h>
#include <hip/hip_bf16.h>

// 16-qubit statevector sim, batch 64. idx bit p ("pos p") of state index; wire w <-> pos 15-w.
// All CRX fused into ctrl-selected 1q gates {M0,M1}. ALL gates are register-bit gates (no
// ds_bpermute) — LDS remaps rotate which 4 positions live in registers. State stored transposed:
// saddr = [pos4..15 -> bits0..11][pos0..3 -> bits12..15] so pB stores and p3 loads both coalesce.
// Pipeline:
//   kprep: M0/M1 per (b,layer,wire); T0/T1 (L0 w13..15 + CRX w12..14); crx15; zero feats/ctr.
//   pA (64 blk): L0 compact 13-bit stage (w0..w12), reg-gate ladder with 3 remaps -> cst (4 MB).
//   pB (512 blk, m=pos1..3): T-expand (block-uniform T!), Gx + L1 w1..w11, 2 remaps, store st.
//   p3 (512 blk, n=pos12..14): L1 w12..15 + CRX15, |amp|^2 + PauliZ sums, last block does FC.

#define NQ 16
#define DIM 65536
#define BATCH 64
#define PSTR 544

// ---------------- gate helpers ----------------

template<int RB>
__device__ __forceinline__ void g1q_reg(float* sr, float* si, const float* U) {
  float u00r=U[0],u00i=U[1],u01r=U[2],u01i=U[3],u10r=U[4],u10i=U[5],u11r=U[6],u11i=U[7];
#pragma unroll
  for (int k = 0; k < 8; ++k) {
    int lo = k & ((1<<RB)-1);
    int j0 = ((k >> RB) << (RB+1)) | lo;
    int j1 = j0 | (1<<RB);
    float a0r=sr[j0], a0i=si[j0], a1r=sr[j1], a1i=si[j1];
    sr[j0] = u00r*a0r - u00i*a0i + u01r*a1r - u01i*a1i;
    si[j0] = u00r*a0i + u00i*a0r + u01r*a1i + u01i*a1r;
    sr[j1] = u10r*a0r - u10i*a0i + u11r*a1r - u11i*a1i;
    si[j1] = u10r*a0i + u10i*a0r + u11r*a1i + u11i*a1r;
  }
}

// fused gate, target reg bit RB, ctrl = reg bit CB (compile-time selection, zero overhead)
template<int RB, int CB>
__device__ __forceinline__ void gsel_reg_cc(float* sr, float* si, const float* M0, const float* M1) {
  float a0=M0[0],a1=M0[1],a2=M0[2],a3=M0[3],a4=M0[4],a5=M0[5],a6=M0[6],a7=M0[7];
  float b0=M1[0],b1=M1[1],b2=M1[2],b3=M1[3],b4=M1[4],b5=M1[5],b6=M1[6],b7=M1[7];
#pragma unroll
  for (int k = 0; k < 8; ++k) {
    int lo = k & ((1<<RB)-1);
    int j0 = ((k >> RB) << (RB+1)) | lo;
    int j1 = j0 | (1<<RB);
    const bool c = ((j0 >> CB) & 1) != 0;
    float u00r=c?b0:a0, u00i=c?b1:a1, u01r=c?b2:a2, u01i=c?b3:a3;
    float u10r=c?b4:a4, u10i=c?b5:a5, u11r=c?b6:a6, u11i=c?b7:a7;
    float p0r=sr[j0], p0i=si[j0], p1r=sr[j1], p1i=si[j1];
    sr[j0] = u00r*p0r - u00i*p0i + u01r*p1r - u01i*p1i;
    si[j0] = u00r*p0i + u00i*p0r + u01r*p1i + u01i*p1r;
    sr[j1] = u10r*p0r - u10i*p0i + u11r*p1r - u11i*p1i;
    si[j1] = u10r*p0i + u10i*p0r + u11r*p1i + u11i*p1r;
  }
}

// fused gate, target reg bit RB, ctrl = runtime predicate (8 cndmask then plain gate)
template<int RB>
__device__ __forceinline__ void gsel_reg_pred(float* sr, float* si, const float* M0,
                                              const float* M1, bool ctrl) {
  float u[8];
#pragma unroll
  for (int e = 0; e < 8; ++e) u[e] = ctrl ? M1[e] : M0[e];
  g1q_reg<RB>(sr, si, u);
}

// fused gate, target lane bit LB, ctrl = reg bit CB (only used once, pA w12)
template<int LB, int CB>
__device__ __forceinline__ void gsel_lane_creg(float* sr, float* si, const float* M0,
                                               const float* M1, int lane) {
  int side = (lane >> LB) & 1;
  float d0r = side ? M0[6] : M0[0], d0i = side ? M0[7] : M0[1];
  float o0r = side ? M0[4] : M0[2], o0i = side ? M0[5] : M0[3];
  float d1r = side ? M1[6] : M1[0], d1i = side ? M1[7] : M1[1];
  float o1r = side ? M1[4] : M1[2], o1i = side ? M1[5] : M1[3];
#pragma unroll
  for (int j = 0; j < 16; ++j) {
    const bool c = ((j >> CB) & 1) != 0;
    float dr = c ? d1r : d0r, di = c ? d1i : d0i;
    float og = c ? o1r : o0r, oi = c ? o1i : o0i;
    float pr = __shfl_xor(sr[j], 1<<LB, 64);
    float pi = __shfl_xor(si[j], 1<<LB, 64);
    float mr = sr[j], mi = si[j];
    sr[j] = dr*mr - di*mi + og*pr - oi*pi;
    si[j] = dr*mi + di*mr + og*pi + oi*pr;
  }
}

// standalone CRX: ctrl reg bit CB, target lane bit LB
template<int CB, int LB>
__device__ __forceinline__ void crx_reg_lane(float* sr, float* si, float c, float s) {
#pragma unroll
  for (int k = 0; k < 8; ++k) {
    int lo2 = k & ((1<<CB)-1);
    int j = ((((k >> CB) << (CB+1)) | lo2)) | (1<<CB);
    float pr = __shfl_xor(sr[j], 1<<LB, 64);
    float pi = __shfl_xor(si[j], 1<<LB, 64);
    float mr = sr[j], mi = si[j];
    sr[j] = c*mr + s*pi;
    si[j] = c*mi - s*pr;
  }
}

// LDS swizzle: 13-bit float2 slot; folds high bits into bank bits (4-way min conflicts verified)
__device__ __forceinline__ int swz(int o) { return o ^ ((o>>4)&15) ^ ((o>>8)&15); }

// ---------------- kprep ----------------

__global__ void kprep(const float* __restrict__ x, const float* __restrict__ w0,
                      const float* __restrict__ x0, const float* __restrict__ w1,
                      const float* __restrict__ x1, float* __restrict__ P,
                      float* __restrict__ crxb, float* __restrict__ feats,
                      int* __restrict__ ctr) {
  __shared__ float su[32][8];
  int b = blockIdx.x;
  int t = threadIdx.x;
  if (t < 16) feats[b*16 + t] = 0.f;
  if (t == 16) ctr[b] = 0;
  if (t < 32) {
    int l = t >> 4, q = t & 15;
    const float* W = (l ? w1 : w0) + q*3;
    float xa = 0.5f * x[b*16 + q];
    float cr = cosf(xa), sx = sinf(xa);
    float phi = W[0], th = W[1], om = W[2];
    float ct = cosf(0.5f*th), stt = sinf(0.5f*th);
    float po = 0.5f*(phi+om), pm = 0.5f*(phi-om);
    float ar =  cosf(po)*ct,  ai = -sinf(po)*ct;
    float br = -cosf(pm)*stt, bi = -sinf(pm)*stt;
    float cr2 = cosf(pm)*stt, ci2 = -sinf(pm)*stt;
    float dr =  cosf(po)*ct,  di =  sinf(po)*ct;
    float U[8];
    U[0] = ar*cr + bi*sx;   U[1] = ai*cr - br*sx;
    U[2] = ai*sx + br*cr;   U[3] = -ar*sx + bi*cr;
    U[4] = cr2*cr + di*sx;  U[5] = ci2*cr - dr*sx;
    U[6] = ci2*sx + dr*cr;  U[7] = -cr2*sx + di*cr;
    float* M0 = P + (size_t)b*PSTR + ((l*16+q)*2+0)*8;
    float* M1 = M0 + 8;
#pragma unroll
    for (int e = 0; e < 8; ++e) { M0[e] = U[e]; su[t][e] = U[e]; }
    if (q == 0) {
      float ang = l ? 0.5f*x0[15] : 0.f;           // boundary: M1 = U * RX
      float cg = cosf(ang), sg = sinf(ang);
      M1[0] =  cg*U[0] + sg*U[3];  M1[1] = cg*U[1] - sg*U[2];
      M1[2] =  sg*U[1] + cg*U[2];  M1[3] = -sg*U[0] + cg*U[3];
      M1[4] =  cg*U[4] + sg*U[7];  M1[5] = cg*U[5] - sg*U[6];
      M1[6] =  sg*U[5] + cg*U[6];  M1[7] = -sg*U[4] + cg*U[7];
    } else {
      float ang = 0.5f*(l ? x1[q-1] : x0[q-1]);    // within layer: M1 = RX * U
      float cg = cosf(ang), sg = sinf(ang);
      M1[0] = cg*U[0] + sg*U[5];  M1[1] = cg*U[1] - sg*U[4];
      M1[2] = cg*U[2] + sg*U[7];  M1[3] = cg*U[3] - sg*U[6];
      M1[4] = cg*U[4] + sg*U[1];  M1[5] = cg*U[5] - sg*U[0];
      M1[6] = cg*U[6] + sg*U[3];  M1[7] = cg*U[7] - sg*U[2];
    }
    if (b == 0 && t == 0) { crxb[0] = cosf(0.5f*x1[15]); crxb[1] = sinf(0.5f*x1[15]); }
  }
  __syncthreads();
  if (t == 0) {
    float T0r[8], T0i[8], T1r[8], T1i[8];
#pragma unroll
    for (int k = 0; k < 8; ++k) {
      int b2 = (k>>2)&1, b1 = (k>>1)&1, b0k = k&1;
      float xr = su[13][b2*4], xi = su[13][b2*4+1];
      float yr = su[14][b1*4], yi = su[14][b1*4+1];
      float zr = su[15][b0k*4], zi = su[15][b0k*4+1];
      float pr = xr*yr - xi*yi, pi = xr*yi + xi*yr;
      T0r[k] = pr*zr - pi*zi; T0i[k] = pr*zi + pi*zr;
    }
    float a12 = 0.5f*x0[12], c12 = cosf(a12), s12 = sinf(a12);
#pragma unroll
    for (int k = 0; k < 8; ++k) { T1r[k] = c12*T0r[k] + s12*T0i[k^4]; T1i[k] = c12*T0i[k] - s12*T0r[k^4]; }
    float a13 = 0.5f*x0[13], c13 = cosf(a13), s13 = sinf(a13);
    float n0r[8], n0i[8], n1r[8], n1i[8];
#pragma unroll
    for (int k = 0; k < 8; ++k) {
      if (k & 4) {
        n0r[k] = c13*T0r[k] + s13*T0i[k^2]; n0i[k] = c13*T0i[k] - s13*T0r[k^2];
        n1r[k] = c13*T1r[k] + s13*T1i[k^2]; n1i[k] = c13*T1i[k] - s13*T1r[k^2];
      } else { n0r[k]=T0r[k]; n0i[k]=T0i[k]; n1r[k]=T1r[k]; n1i[k]=T1i[k]; }
    }
    float a14 = 0.5f*x0[14], c14 = cosf(a14), s14 = sinf(a14);
    float* T0 = P + (size_t)b*PSTR + 512;
    float* T1 = T0 + 16;
#pragma unroll
    for (int k = 0; k < 8; ++k) {
      float r0, i0, r1, i1;
      if (k & 2) {
        r0 = c14*n0r[k] + s14*n0i[k^1]; i0 = c14*n0i[k] - s14*n0r[k^1];
        r1 = c14*n1r[k] + s14*n1i[k^1]; i1 = c14*n1i[k] - s14*n1r[k^1];
      } else { r0=n0r[k]; i0=n0i[k]; r1=n1r[k]; i1=n1i[k]; }
      T0[2*k] = r0; T0[2*k+1] = i0; T1[2*k] = r1; T1[2*k+1] = i1;
    }
  }
}

#define MP(Pb, l, q, s) ((Pb) + (((l)*16+(q))*2+(s))*8)

// ---------------- pA: L0 compact 13-bit stage (w0..w12), reg-gate ladder ----------------
// tile offset o = j (13 bits). Layouts:
// L1: reg=j9..12, l0..5=j3..8, wv=j0..2     L2: reg=j5..8, l0..3=j9..12, l4,5=j3,j4, wv=j0..2
// L3: reg=j1..4, l0=j0, l1..5=j5..9, wv=j10..12
// L4(store): reg=j9..12, l0..5=j1..6, wv0,1=j7,j8, wv2=j0
// cst caddr = [j9..12][j1..6][j7,j8][j0]

__global__ __launch_bounds__(512) void pA(float4* __restrict__ cst4, const float* __restrict__ P) {
  __shared__ float2 lds2[8192];
  int b = blockIdx.x;
  int t = threadIdx.x, lane = t & 63, wv = t >> 6;
  const float* Pb = P + (size_t)b*PSTR;

  float sr[16], si[16];
#pragma unroll
  for (int r = 0; r < 16; ++r) { sr[r] = 0.f; si[r] = 0.f; }
  if (t == 0) sr[0] = 1.f;

  // L1: w0..w3 (tgt j12..j9 = reg3..0)
  g1q_reg<3>(sr, si, MP(Pb,0,0,0));
  gsel_reg_cc<2,3>(sr, si, MP(Pb,0,1,0), MP(Pb,0,1,1));
  gsel_reg_cc<1,2>(sr, si, MP(Pb,0,2,0), MP(Pb,0,2,1));
  gsel_reg_cc<0,1>(sr, si, MP(Pb,0,3,0), MP(Pb,0,3,1));

  // remap L1 -> L2
#pragma unroll
  for (int r = 0; r < 16; ++r) {
    int o = wv | (lane << 3) | (r << 9);
    lds2[swz(o)] = make_float2(sr[r], si[r]);
  }
  __syncthreads();
#pragma unroll
  for (int r = 0; r < 16; ++r) {
    int o = wv | (((lane>>4)&3) << 3) | (r << 5) | ((lane&15) << 9);
    float2 v = lds2[swz(o)]; sr[r] = v.x; si[r] = v.y;
  }

  // L2: w4..w7 (tgt j8..j5 = reg3..0); w4 ctrl j9 = l0
  gsel_reg_pred<3>(sr, si, MP(Pb,0,4,0), MP(Pb,0,4,1), (lane&1)!=0);
  gsel_reg_cc<2,3>(sr, si, MP(Pb,0,5,0), MP(Pb,0,5,1));
  gsel_reg_cc<1,2>(sr, si, MP(Pb,0,6,0), MP(Pb,0,6,1));
  gsel_reg_cc<0,1>(sr, si, MP(Pb,0,7,0), MP(Pb,0,7,1));

  // remap L2 -> L3
  __syncthreads();
#pragma unroll
  for (int r = 0; r < 16; ++r) {
    int o = wv | (((lane>>4)&3) << 3) | (r << 5) | ((lane&15) << 9);
    lds2[swz(o)] = make_float2(sr[r], si[r]);
  }
  __syncthreads();
#pragma unroll
  for (int r = 0; r < 16; ++r) {
    int o = (lane&1) | (r << 1) | (((lane>>1)&31) << 5) | (wv << 10);
    float2 v = lds2[swz(o)]; sr[r] = v.x; si[r] = v.y;
  }

  // L3: w8..w11 (tgt j4..j1 = reg3..0); w8 ctrl j5 = l1; then w12 (tgt j0 = l0, ctrl j1 = reg0)
  gsel_reg_pred<3>(sr, si, MP(Pb,0,8,0), MP(Pb,0,8,1), (lane&2)!=0);
  gsel_reg_cc<2,3>(sr, si, MP(Pb,0,9,0), MP(Pb,0,9,1));
  gsel_reg_cc<1,2>(sr, si, MP(Pb,0,10,0), MP(Pb,0,10,1));
  gsel_reg_cc<0,1>(sr, si, MP(Pb,0,11,0), MP(Pb,0,11,1));
  gsel_lane_creg<0,0>(sr, si, MP(Pb,0,12,0), MP(Pb,0,12,1), lane);

  // remap L3 -> L4, store compact state
  __syncthreads();
#pragma unroll
  for (int r = 0; r < 16; ++r) {
    int o = (lane&1) | (r << 1) | (((lane>>1)&31) << 5) | (wv << 10);
    lds2[swz(o)] = make_float2(sr[r], si[r]);
  }
  __syncthreads();
#pragma unroll
  for (int r = 0; r < 16; ++r) {
    int o = ((wv>>2)&1) | (lane << 1) | ((wv&3) << 7) | (r << 9);
    float2 v = lds2[swz(o)]; sr[r] = v.x; si[r] = v.y;
  }
  {
    int base4 = (lane << 3) | ((wv&3) << 9) | (((wv>>2)&1) << 11);
    float4* dst = cst4 + (size_t)b*4096 + base4;
#pragma unroll
    for (int g = 0; g < 8; ++g)
      dst[g] = make_float4(sr[2*g], si[2*g], sr[2*g+1], si[2*g+1]);
  }
}

// ---------------- pB: T-expand + Gx + L1 w1..w11, store transposed state ----------------
// block m = pos1,2,3. tile o: o0..11 = pos4..15, o12 = pos0 (= wv2 throughout).
// LA: reg=pos12..15, l0..5=pos4..9, wv0,1=pos10,11
// LB: reg=pos8..11, l0..3=pos4..7, l4,5=pos12,13, wv0,1=pos14,15
// LC: reg=pos4..7, l0..5=pos8..13, wv0,1=pos14,15
// store saddr = o | (m<<13)

__global__ __launch_bounds__(512) void pB(float2* __restrict__ st, const float4* __restrict__ cst4,
                                          const float* __restrict__ P) {
  __shared__ float2 lds2[8192];
  int blk = blockIdx.x;
  int b = blk >> 3, m = blk & 7;
  int t = threadIdx.x, lane = t & 63, wv = t >> 6;
  const float* Pb = P + (size_t)b*PSTR;

  // load full compact state slice + expand (T is block/wave-uniform: pos0=wv2, pos1..3=m)
  float sr[16], si[16];
  {
    const float4* src = cst4 + (size_t)b*4096 + ((lane << 3) | ((wv&3) << 9) | (((m>>2)&1) << 11));
    const float* Ts = ((m>>2)&1) ? (Pb + 528) : (Pb + 512);
    int k = ((wv>>2)&1) | ((m&1) << 1) | (((m>>1)&1) << 2);
    float tr = Ts[2*k], ti = Ts[2*k+1];
#pragma unroll
    for (int g = 0; g < 8; ++g) {
      float4 v = src[g];
      sr[2*g]   = tr*v.x - ti*v.y;  si[2*g]   = tr*v.y + ti*v.x;
      sr[2*g+1] = tr*v.z - ti*v.w;  si[2*g+1] = tr*v.w + ti*v.z;
    }
  }

  // LA: Gx (L1 w0, tgt pos15=reg3, ctrl pos0=wv2), w1..w3 (tgt pos14..12 = reg2..0)
  gsel_reg_pred<3>(sr, si, MP(Pb,1,0,0), MP(Pb,1,0,1), ((wv>>2)&1)!=0);
  gsel_reg_cc<2,3>(sr, si, MP(Pb,1,1,0), MP(Pb,1,1,1));
  gsel_reg_cc<1,2>(sr, si, MP(Pb,1,2,0), MP(Pb,1,2,1));
  gsel_reg_cc<0,1>(sr, si, MP(Pb,1,3,0), MP(Pb,1,3,1));

  // remap LA -> LB
#pragma unroll
  for (int r = 0; r < 16; ++r) {
    int o = (lane&63) | ((wv&3) << 6) | (r << 8) | (((wv>>2)&1) << 12);
    lds2[swz(o)] = make_float2(sr[r], si[r]);
  }
  __syncthreads();
#pragma unroll
  for (int r = 0; r < 16; ++r) {
    int o = (lane&15) | (r << 4) | (((lane>>4)&3) << 8) | ((wv&3) << 10) | (((wv>>2)&1) << 12);
    float2 v = lds2[swz(o)]; sr[r] = v.x; si[r] = v.y;
  }

  // LB: w4 (tgt pos11=reg3, ctrl pos12=l4), w5..w7 (tgt pos10..8 = reg2..0)
  gsel_reg_pred<3>(sr, si, MP(Pb,1,4,0), MP(Pb,1,4,1), (lane&16)!=0);
  gsel_reg_cc<2,3>(sr, si, MP(Pb,1,5,0), MP(Pb,1,5,1));
  gsel_reg_cc<1,2>(sr, si, MP(Pb,1,6,0), MP(Pb,1,6,1));
  gsel_reg_cc<0,1>(sr, si, MP(Pb,1,7,0), MP(Pb,1,7,1));

  // remap LB -> LC
  __syncthreads();
#pragma unroll
  for (int r = 0; r < 16; ++r) {
    int o = (lane&15) | (r << 4) | (((lane>>4)&3) << 8) | ((wv&3) << 10) | (((wv>>2)&1) << 12);
    lds2[swz(o)] = make_float2(sr[r], si[r]);
  }
  __syncthreads();
#pragma unroll
  for (int r = 0; r < 16; ++r) {
    int o = r | ((lane&63) << 4) | ((wv&3) << 10) | (((wv>>2)&1) << 12);
    float2 v = lds2[swz(o)]; sr[r] = v.x; si[r] = v.y;
  }

  // LC: w8 (tgt pos7=reg3, ctrl pos8=l0), w9..w11 (tgt pos6..4 = reg2..0)
  gsel_reg_pred<3>(sr, si, MP(Pb,1,8,0), MP(Pb,1,8,1), (lane&1)!=0);
  gsel_reg_cc<2,3>(sr, si, MP(Pb,1,9,0), MP(Pb,1,9,1));
  gsel_reg_cc<1,2>(sr, si, MP(Pb,1,10,0), MP(Pb,1,10,1));
  gsel_reg_cc<0,1>(sr, si, MP(Pb,1,11,0), MP(Pb,1,11,1));

  // store transposed state: saddr0..3 = reg (pos4..7) -> 8 contiguous float4
  {
    int sbase = ((lane&63) << 4) | ((wv&3) << 10) | (((wv>>2)&1) << 12) | (m << 13);
    float4* dst = (float4*)(st + (size_t)b*DIM + sbase);
#pragma unroll
    for (int g = 0; g < 8; ++g)
      dst[g] = make_float4(sr[2*g], si[2*g], sr[2*g+1], si[2*g+1]);
  }
}

// ---------------- p3: L1 w12..15 + CRX15, observables, last-block FC ----------------
// block n = pos12,13,14 (saddr8..10). reg = pos0..3 (saddr12..15), l0..4 = pos4..8 (saddr0..4),
// l5 = pos15 (saddr11), wv = pos9,10,11 (saddr5..7).

__global__ __launch_bounds__(512) void p3(const float2* __restrict__ st, const float* __restrict__ P,
                                          const float* __restrict__ crxb, float* __restrict__ feats,
                                          int* __restrict__ ctr, const float* __restrict__ fcw,
                                          const float* __restrict__ fcb, float* __restrict__ out) {
  int blk = blockIdx.x;
  int b = blk >> 3, n = blk & 7;
  int t = threadIdx.x, lane = t & 63, wv = t >> 6;
  const float* Pb = P + (size_t)b*PSTR;
  int base = (lane&31) | (wv << 5) | (n << 8) | ((lane>>5) << 11);
  const float2* S = st + (size_t)b*DIM + base;
  float sr[16], si[16];
#pragma unroll
  for (int r = 0; r < 16; ++r) { float2 v = S[r << 12]; sr[r] = v.x; si[r] = v.y; }

  // w12 (tgt pos3=reg3, ctrl pos4=l0), w13..w15 (tgt pos2..0 = reg2..0), CRX15 (ctrl pos0=reg0, tgt pos15=l5)
  gsel_reg_pred<3>(sr, si, MP(Pb,1,12,0), MP(Pb,1,12,1), (lane&1)!=0);
  gsel_reg_cc<2,3>(sr, si, MP(Pb,1,13,0), MP(Pb,1,13,1));
  gsel_reg_cc<1,2>(sr, si, MP(Pb,1,14,0), MP(Pb,1,14,1));
  gsel_reg_cc<0,1>(sr, si, MP(Pb,1,15,0), MP(Pb,1,15,1));
  crx_reg_lane<0,5>(sr, si, crxb[0], crxb[1]);

  float tot=0.f, sA=0.f, sB=0.f, sC=0.f, sD=0.f;
#pragma unroll
  for (int r = 0; r < 16; ++r) {
    float p = sr[r]*sr[r] + si[r]*si[r];
    tot += p;
    sA += (r & 1) ? -p : p;   // pos0 -> wire15
    sB += (r & 2) ? -p : p;   // pos1 -> wire14
    sC += (r & 4) ? -p : p;   // pos2 -> wire13
    sD += (r & 8) ? -p : p;   // pos3 -> wire12
  }
  float f[16];
  f[15] = sA; f[14] = sB; f[13] = sC; f[12] = sD;
  f[11] = (lane&1)  ? -tot : tot;   // pos4
  f[10] = (lane&2)  ? -tot : tot;   // pos5
  f[9]  = (lane&4)  ? -tot : tot;   // pos6
  f[8]  = (lane&8)  ? -tot : tot;   // pos7
  f[7]  = (lane&16) ? -tot : tot;   // pos8
  f[0]  = (lane&32) ? -tot : tot;   // pos15
  f[6]  = (wv&1)    ? -tot : tot;   // pos9
  f[5]  = (wv&2)    ? -tot : tot;   // pos10
  f[4]  = (wv&4)    ? -tot : tot;   // pos11
  f[3]  = (n&1)     ? -tot : tot;   // pos12
  f[2]  = (n&2)     ? -tot : tot;   // pos13
  f[1]  = (n&4)     ? -tot : tot;   // pos14
#pragma unroll
  for (int w = 0; w < 16; ++w) {
#pragma unroll
    for (int off = 32; off; off >>= 1) f[w] += __shfl_xor(f[w], off, 64);
  }
  __shared__ float red[8][17];
  if (lane == 0) {
#pragma unroll
    for (int w = 0; w < 16; ++w) red[wv][w] = f[w];
  }
  __syncthreads();
  if (t < 16) {
    float acc = 0.f;
#pragma unroll
    for (int i = 0; i < 8; ++i) acc += red[i][t];
    atomicAdd(&feats[b*16 + t], acc);
  }

  // last block per batch computes FC + log_softmax
  __shared__ int flagS;
  __syncthreads();
  if (t == 0) { __threadfence(); flagS = atomicAdd(&ctr[b], 1); }
  __syncthreads();
  if (flagS == 7) {
    __shared__ float fs[16];
    __shared__ float lg[23];
    if (t < 16) fs[t] = __hip_atomic_load(&feats[b*16 + t], __ATOMIC_RELAXED, __HIP_MEMORY_SCOPE_AGENT);
    __syncthreads();
    if (t < 23) {
      float acc = fcb[t];
#pragma unroll
      for (int w = 0; w < 16; ++w) acc += fs[w] * fcw[t*16 + w];
      lg[t] = acc;
    }
    __syncthreads();
    if (t < 23) {
      float mx = -1e30f;
#pragma unroll
      for (int j = 0; j < 23; ++j) mx = fmaxf(mx, lg[j]);
      float Ssum = 0.f;
#pragma unroll
      for (int j = 0; j < 23; ++j) Ssum += expf(lg[j] - mx);
      out[b*23 + t] = lg[t] - mx - logf(Ssum);
    }
  }
}

extern "C" void kernel_launch(void* const* d_in, const int* in_sizes, int n_in,
                              void* d_out, int out_size, void* d_ws, size_t ws_size,
                              hipStream_t stream) {
  const float* x   = (const float*)d_in[0];
  const float* w0  = (const float*)d_in[1];
  const float* x0  = (const float*)d_in[2];
  const float* w1  = (const float*)d_in[3];
  const float* x1  = (const float*)d_in[4];
  const float* fcw = (const float*)d_in[5];
  const float* fcb = (const float*)d_in[6];
  float* out = (float*)d_out;

  char* ws = (char*)d_ws;
  float2* st   = (float2*)ws;                                          // 32 MB
  float4* cst4 = (float4*)(ws + (size_t)BATCH * DIM * sizeof(float2)); // 4 MB
  float*  P    = (float*)((char*)cst4 + (size_t)BATCH * 8192 * sizeof(float2));
  float*  crxb = P + (size_t)BATCH * PSTR;
  float*  feats = crxb + 16;
  int*    ctr  = (int*)(feats + BATCH*16);

  kprep<<<BATCH, 64, 0, stream>>>(x, w0, x0, w1, x1, P, crxb, feats, ctr);
  pA<<<BATCH, 512, 0, stream>>>(cst4, P);
  pB<<<512, 512, 0, stream>>>(st, cst4, P);
  p3<<<512, 512, 0, stream>>>(st, P, crxb, feats, ctr, fcw, fcb, out);
  (void)in_sizes; (void)n_in; (void)out_size; (void)ws_size;
}